// Round 1
// baseline (275.124 us; speedup 1.0000x reference)
//
#include <hip/hip_runtime.h>
#include <hip/hip_bf16.h>
#include <math.h>

// Problem dims (fixed by setup_inputs): B=4, N=4096, C=128, H=512, S=32
static constexpr int BB = 4;
static constexpr int NN = 4096;
static constexpr int CC = 128;
static constexpr int HH = 512;
static constexpr int SS = 32;
static constexpr float EPSF = 1e-5f;

// ---------------------------------------------------------------------------
// Ball query: one wave (64 threads) per query point. Scan all N candidates in
// index order; first 32 within radius kept; remainder filled with first.
// ---------------------------------------------------------------------------
__global__ __launch_bounds__(64)
void ball_query_kernel(const float* __restrict__ xyz, int* __restrict__ idx)
{
    const int p    = blockIdx.x;        // b*N + n
    const int b    = p >> 12;           // / 4096
    const int n    = p & (NN - 1);
    const int lane = threadIdx.x;

    const float* base = xyz + (size_t)b * NN * 3;
    const float qx = base[n * 3 + 0];
    const float qy = base[n * 3 + 1];
    const float qz = base[n * 3 + 2];

    __shared__ int sj[SS];
    int cnt = 0;

    for (int j0 = 0; j0 < NN; j0 += 64) {
        const int j = j0 + lane;
        float sq;
        {
            // match numpy: no FMA contraction at the radius boundary
            #pragma clang fp contract(off)
            const float dx = qx - base[j * 3 + 0];
            const float dy = qy - base[j * 3 + 1];
            const float dz = qz - base[j * 3 + 2];
            sq = dx * dx + dy * dy + dz * dz;
        }
        const bool in = (sq <= 0.01f);  // 0.01f == f32(radius*radius) in jax
        const unsigned long long mask = __ballot(in);
        if (in) {
            const int pos = cnt + __popcll(mask & ((1ull << lane) - 1ull));
            if (pos < SS) sj[pos] = j;
        }
        cnt += (int)__popcll(mask);
        if (cnt >= SS) break;           // wave-uniform
    }
    __syncthreads();

    if (lane < SS) {
        const int first = sj[0];        // self (j==n) always in-radius -> cnt>=1
        const int v = (lane < cnt) ? sj[lane] : first;
        idx[(size_t)p * SS + lane] = v;
    }
}

// ---------------------------------------------------------------------------
// Pack Wn[:, 3:131] -> contiguous 128x128 (aligned rows for float4 GEMM loads)
// ---------------------------------------------------------------------------
__global__ __launch_bounds__(256)
void pack_wn_kernel(const float* __restrict__ Wn, float* __restrict__ WnF)
{
    const int i = blockIdx.x * 256 + threadIdx.x;
    if (i < CC * CC) {
        const int o = i >> 7;
        const int c = i & 127;
        WnF[i] = Wn[o * 131 + 3 + c];
    }
}

// ---------------------------------------------------------------------------
// Stage 1 fused: per point, out[o] = relu( max_s ( bn( T[b,idx_s,o]
//                + Wn[o,0:3] . (xyz[idx_s]-xyz[n])/R ) ) )
// Block = 128 threads (one per output channel), one block per point.
// ---------------------------------------------------------------------------
__global__ __launch_bounds__(128)
void group_max_kernel(const float* __restrict__ xyz, const float* __restrict__ T,
                      const float* __restrict__ Wn,
                      const float* __restrict__ gn, const float* __restrict__ bnv,
                      const float* __restrict__ mn, const float* __restrict__ vn,
                      const int* __restrict__ idx, float* __restrict__ xout)
{
    const int p = blockIdx.x;           // b*N + n
    const int b = p >> 12;
    const int o = threadIdx.x;          // 0..127

    __shared__ int   sj[SS];
    __shared__ float sgx[SS][3];

    const float* xb = xyz + (size_t)b * NN * 3;
    const float* q  = xyz + (size_t)p * 3;

    if (o < SS) {
        const int j = idx[(size_t)p * SS + o];
        sj[o] = j;
        sgx[o][0] = (xb[j * 3 + 0] - q[0]) / 0.1f;
        sgx[o][1] = (xb[j * 3 + 1] - q[1]) / 0.1f;
        sgx[o][2] = (xb[j * 3 + 2] - q[2]) / 0.1f;
    }
    __syncthreads();

    const float w0 = Wn[o * 131 + 0];
    const float w1 = Wn[o * 131 + 1];
    const float w2 = Wn[o * 131 + 2];
    const float sc = gn[o] / sqrtf(vn[o] + EPSF);
    const float sh = bnv[o] - mn[o] * sc;

    const float* Tb = T + (size_t)b * NN * CC;
    float mx = -INFINITY;
    #pragma unroll 8
    for (int s = 0; s < SS; ++s) {
        const float pre = Tb[(size_t)sj[s] * CC + o]
                        + w0 * sgx[s][0] + w1 * sgx[s][1] + w2 * sgx[s][2];
        mx = fmaxf(mx, fmaf(sc, pre, sh));
    }
    xout[(size_t)p * CC + o] = fmaxf(mx, 0.0f);   // relu(max) == max(relu)
}

// ---------------------------------------------------------------------------
// Generic fp32 GEMM: out[m,o] = epilogue( dot(A[m,:K], W[o,:K]) )
// Tile 64(M) x 128(N), BK=32, 256 threads, 4x8 micro-tile.
// MODE 0: plain store           (T = feats @ WnF^T)
// MODE 1: relu(bn(z))           (h = relu(bn(x @ W1^T)))
// MODE 2: relu(bn(z) + res)     (out = relu(bn(h @ W2^T) + feats))
// ---------------------------------------------------------------------------
template<int MODE>
__global__ __launch_bounds__(256)
void gemm_kernel(const float* __restrict__ A, const float* __restrict__ W,
                 const float* __restrict__ g, const float* __restrict__ bb,
                 const float* __restrict__ mu, const float* __restrict__ var,
                 const float* __restrict__ res, float* __restrict__ out,
                 int M, int Nout, int K)
{
    __shared__ float As[32][68];    // [k][m], padded: 2-way max on reads
    __shared__ float Ws[32][132];   // [k][o], padded

    const int t  = threadIdx.x;
    const int m0 = blockIdx.x * 64;
    const int o0 = blockIdx.y * 128;
    const int tm = t & 15;          // m sub-row   (4 rows each)
    const int tn = t >> 4;          // o sub-col   (8 cols each)

    float acc[4][8];
    #pragma unroll
    for (int i = 0; i < 4; ++i)
        #pragma unroll
        for (int j = 0; j < 8; ++j) acc[i][j] = 0.0f;

    for (int kc = 0; kc < K; kc += 32) {
        // A tile: 64 rows x 32 k = 512 float4 -> 2 per thread
        #pragma unroll
        for (int l = 0; l < 2; ++l) {
            const int id  = t + l * 256;
            const int row = id >> 3;
            const int c4  = (id & 7) << 2;
            const float4 a = *(const float4*)(A + (size_t)(m0 + row) * K + kc + c4);
            As[c4 + 0][row] = a.x; As[c4 + 1][row] = a.y;
            As[c4 + 2][row] = a.z; As[c4 + 3][row] = a.w;
        }
        // W tile: 128 rows x 32 k = 1024 float4 -> 4 per thread
        #pragma unroll
        for (int l = 0; l < 4; ++l) {
            const int id  = t + l * 256;
            const int row = id >> 3;
            const int c4  = (id & 7) << 2;
            const float4 w = *(const float4*)(W + (size_t)(o0 + row) * K + kc + c4);
            Ws[c4 + 0][row] = w.x; Ws[c4 + 1][row] = w.y;
            Ws[c4 + 2][row] = w.z; Ws[c4 + 3][row] = w.w;
        }
        __syncthreads();

        #pragma unroll
        for (int k = 0; k < 32; ++k) {
            const float4 av  = *(const float4*)&As[k][tm << 2];
            const float4 wv0 = *(const float4*)&Ws[k][tn << 3];
            const float4 wv1 = *(const float4*)&Ws[k][(tn << 3) + 4];
            const float aa[4] = {av.x, av.y, av.z, av.w};
            const float ww[8] = {wv0.x, wv0.y, wv0.z, wv0.w,
                                 wv1.x, wv1.y, wv1.z, wv1.w};
            #pragma unroll
            for (int i = 0; i < 4; ++i)
                #pragma unroll
                for (int j = 0; j < 8; ++j)
                    acc[i][j] = fmaf(aa[i], ww[j], acc[i][j]);
        }
        __syncthreads();
    }

    // epilogue
    float sc[8], sh[8], mm[8];
    if constexpr (MODE >= 1) {
        #pragma unroll
        for (int j = 0; j < 8; ++j) {
            const int o = o0 + (tn << 3) + j;
            sc[j] = g[o] / sqrtf(var[o] + EPSF);
            sh[j] = bb[o];
            mm[j] = mu[o];
        }
    }
    #pragma unroll
    for (int i = 0; i < 4; ++i) {
        const int m = m0 + (tm << 2) + i;
        float vv[8];
        #pragma unroll
        for (int j = 0; j < 8; ++j) {
            float z = acc[i][j];
            if constexpr (MODE >= 1) z = fmaf(z - mm[j], sc[j], sh[j]);
            vv[j] = z;
        }
        if constexpr (MODE == 2) {
            const float4 r0 = *(const float4*)(res + (size_t)m * Nout + o0 + (tn << 3));
            const float4 r1 = *(const float4*)(res + (size_t)m * Nout + o0 + (tn << 3) + 4);
            vv[0] += r0.x; vv[1] += r0.y; vv[2] += r0.z; vv[3] += r0.w;
            vv[4] += r1.x; vv[5] += r1.y; vv[6] += r1.z; vv[7] += r1.w;
        }
        if constexpr (MODE >= 1) {
            #pragma unroll
            for (int j = 0; j < 8; ++j) vv[j] = fmaxf(vv[j], 0.0f);
        }
        float4 s0 = {vv[0], vv[1], vv[2], vv[3]};
        float4 s1 = {vv[4], vv[5], vv[6], vv[7]};
        *(float4*)(out + (size_t)m * Nout + o0 + (tn << 3))     = s0;
        *(float4*)(out + (size_t)m * Nout + o0 + (tn << 3) + 4) = s1;
    }
}

// ---------------------------------------------------------------------------
extern "C" void kernel_launch(void* const* d_in, const int* in_sizes, int n_in,
                              void* d_out, int out_size, void* d_ws, size_t ws_size,
                              hipStream_t stream)
{
    const float* xyz   = (const float*)d_in[0];
    const float* feats = (const float*)d_in[1];
    const float* Wn    = (const float*)d_in[2];
    const float* gn    = (const float*)d_in[3];
    const float* bn_   = (const float*)d_in[4];
    const float* mn    = (const float*)d_in[5];
    const float* vn    = (const float*)d_in[6];
    const float* W1    = (const float*)d_in[7];
    const float* g1    = (const float*)d_in[8];
    const float* b1    = (const float*)d_in[9];
    const float* m1    = (const float*)d_in[10];
    const float* v1    = (const float*)d_in[11];
    const float* W2    = (const float*)d_in[12];
    const float* g2    = (const float*)d_in[13];
    const float* b2    = (const float*)d_in[14];
    const float* m2    = (const float*)d_in[15];
    const float* v2    = (const float*)d_in[16];
    float* out = (float*)d_out;

    // workspace layout (all 256B-aligned offsets)
    char* ws = (char*)d_ws;
    int*   idx = (int*)(ws);                         //  0       .. 2 MB
    float* WnF = (float*)(ws + 2097152);             //  2 MB    .. +64 KB
    float* T   = (float*)(ws + 2162688);             //  ~2.06MB .. +8 MB
    float* x   = (float*)(ws + 10551296);            //  ~10.1MB .. +8 MB
    float* h   = (float*)(ws + 18939904);            //  ~18.1MB .. +32 MB  (total ~50.1 MB)

    const int M = BB * NN;  // 16384

    hipLaunchKernelGGL(pack_wn_kernel, dim3(64), dim3(256), 0, stream, Wn, WnF);

    hipLaunchKernelGGL(ball_query_kernel, dim3(M), dim3(64), 0, stream, xyz, idx);

    // T = feats @ WnF^T   (M x 128, K=128)
    hipLaunchKernelGGL((gemm_kernel<0>), dim3(M / 64, CC / 128), dim3(256), 0, stream,
                       feats, WnF, nullptr, nullptr, nullptr, nullptr, nullptr,
                       T, M, CC, CC);

    // x = relu(max_s bn1(T_gather + xyz-part))
    hipLaunchKernelGGL(group_max_kernel, dim3(M), dim3(128), 0, stream,
                       xyz, T, Wn, gn, bn_, mn, vn, idx, x);

    // h = relu(bn(x @ W1^T))   (M x 512, K=128)
    hipLaunchKernelGGL((gemm_kernel<1>), dim3(M / 64, HH / 128), dim3(256), 0, stream,
                       x, W1, g1, b1, m1, v1, nullptr, h, M, HH, CC);

    // out = relu(bn(h @ W2^T) + feats)   (M x 128, K=512)
    hipLaunchKernelGGL((gemm_kernel<2>), dim3(M / 64, CC / 128), dim3(256), 0, stream,
                       h, W2, g2, b2, m2, v2, feats, out, M, CC, HH);
}

// Round 2
// 208.620 us; speedup vs baseline: 1.3188x; 1.3188x over previous
//
#include <hip/hip_runtime.h>
#include <hip/hip_bf16.h>
#include <math.h>

// Problem dims (fixed by setup_inputs): B=4, N=4096, C=128, H=512, S=32
static constexpr int BB = 4;
static constexpr int NN = 4096;
static constexpr int CC = 128;
static constexpr int HH = 512;
static constexpr int SS = 32;
static constexpr float EPSF = 1e-5f;

typedef __bf16 bf16_t;
typedef bf16_t bf16x8 __attribute__((ext_vector_type(8)));
typedef float f32x4 __attribute__((ext_vector_type(4)));

__device__ inline unsigned short f2bf(float f) {
    unsigned int u = __builtin_bit_cast(unsigned int, f);
    u += 0x7FFFu + ((u >> 16) & 1u);          // RNE
    return (unsigned short)(u >> 16);
}
__device__ inline float bf2f(unsigned short s) {
    unsigned int u = ((unsigned int)s) << 16;
    return __builtin_bit_cast(float, u);
}

__device__ inline void gload_lds16(const void* g, void* l) {
    __builtin_amdgcn_global_load_lds(
        (const __attribute__((address_space(1))) unsigned int*)g,
        (__attribute__((address_space(3))) unsigned int*)l, 16, 0, 0);
}

// ---------------------------------------------------------------------------
// Ball query: one wave per query point; first 32 in-radius by index order.
// ---------------------------------------------------------------------------
__global__ __launch_bounds__(64)
void ball_query_kernel(const float* __restrict__ xyz, int* __restrict__ idx)
{
    const int p    = blockIdx.x;        // b*N + n
    const int b    = p >> 12;
    const int n    = p & (NN - 1);
    const int lane = threadIdx.x;

    const float* base = xyz + (size_t)b * NN * 3;
    const float qx = base[n * 3 + 0];
    const float qy = base[n * 3 + 1];
    const float qz = base[n * 3 + 2];

    __shared__ int sj[SS];
    int cnt = 0;

    for (int j0 = 0; j0 < NN; j0 += 64) {
        const int j = j0 + lane;
        float sq;
        {
            #pragma clang fp contract(off)   // match numpy (no FMA at boundary)
            const float dx = qx - base[j * 3 + 0];
            const float dy = qy - base[j * 3 + 1];
            const float dz = qz - base[j * 3 + 2];
            sq = dx * dx + dy * dy + dz * dz;
        }
        const bool in = (sq <= 0.01f);
        const unsigned long long mask = __ballot(in);
        if (in) {
            const int pos = cnt + __popcll(mask & ((1ull << lane) - 1ull));
            if (pos < SS) sj[pos] = j;
        }
        cnt += (int)__popcll(mask);
        if (cnt >= SS) break;               // wave-uniform
    }
    __syncthreads();

    if (lane < SS) {
        const int first = sj[0];            // self always in-radius
        idx[(size_t)p * SS + lane] = (lane < cnt) ? sj[lane] : first;
    }
}

// ---------------------------------------------------------------------------
// Pack weights to bf16: WnF = Wn[:,3:131] (128x128), W1b (512x128), W2b (128x512)
// ---------------------------------------------------------------------------
__global__ __launch_bounds__(256)
void pack_weights_kernel(const float* __restrict__ Wn, const float* __restrict__ W1,
                         const float* __restrict__ W2,
                         unsigned short* __restrict__ WnF,
                         unsigned short* __restrict__ W1b,
                         unsigned short* __restrict__ W2b)
{
    const int i = blockIdx.x * 256 + threadIdx.x;
    if (i < 16384) {
        const int o = i >> 7, c = i & 127;
        WnF[i] = f2bf(Wn[o * 131 + 3 + c]);
    } else if (i < 16384 + 65536) {
        const int k = i - 16384;
        W1b[k] = f2bf(W1[k]);
    } else if (i < 16384 + 131072) {
        const int k = i - 16384 - 65536;
        W2b[k] = f2bf(W2[k]);
    }
}

// feats fp32 -> bf16, 4 elements per thread
__global__ __launch_bounds__(256)
void convert_feats_kernel(const float* __restrict__ f, unsigned short* __restrict__ fb)
{
    const int i = blockIdx.x * 256 + threadIdx.x;   // handles elements 4i..4i+3
    const float4 v = ((const float4*)f)[i];
    unsigned long long pk = (unsigned long long)f2bf(v.x)
                          | ((unsigned long long)f2bf(v.y) << 16)
                          | ((unsigned long long)f2bf(v.z) << 32)
                          | ((unsigned long long)f2bf(v.w) << 48);
    ((unsigned long long*)fb)[i] = pk;
}

// ---------------------------------------------------------------------------
// Stage 1 fused: x[p,o] = relu( max_s bn1( T[b,idx_s,o] + Wn[o,0:3].gxyz_s ) )
// Block = 128 threads (one per channel). T bf16 in, x bf16 out.
// ---------------------------------------------------------------------------
__global__ __launch_bounds__(128)
void group_max_kernel(const float* __restrict__ xyz, const unsigned short* __restrict__ T,
                      const float* __restrict__ Wn,
                      const float* __restrict__ gn, const float* __restrict__ bnv,
                      const float* __restrict__ mn, const float* __restrict__ vn,
                      const int* __restrict__ idx, unsigned short* __restrict__ xout)
{
    const int p = blockIdx.x;
    const int b = p >> 12;
    const int o = threadIdx.x;

    __shared__ int   sj[SS];
    __shared__ float sgx[SS][3];

    const float* xb = xyz + (size_t)b * NN * 3;
    const float* q  = xyz + (size_t)p * 3;

    if (o < SS) {
        const int j = idx[(size_t)p * SS + o];
        sj[o] = j;
        sgx[o][0] = (xb[j * 3 + 0] - q[0]) / 0.1f;
        sgx[o][1] = (xb[j * 3 + 1] - q[1]) / 0.1f;
        sgx[o][2] = (xb[j * 3 + 2] - q[2]) / 0.1f;
    }
    __syncthreads();

    const float w0 = Wn[o * 131 + 0];
    const float w1 = Wn[o * 131 + 1];
    const float w2 = Wn[o * 131 + 2];
    const float sc = gn[o] / sqrtf(vn[o] + EPSF);
    const float sh = bnv[o] - mn[o] * sc;

    const unsigned short* Tb = T + (size_t)b * NN * CC;
    float mx = -INFINITY;
    #pragma unroll 8
    for (int s = 0; s < SS; ++s) {
        const float pre = bf2f(Tb[(size_t)sj[s] * CC + o])
                        + w0 * sgx[s][0] + w1 * sgx[s][1] + w2 * sgx[s][2];
        mx = fmaxf(mx, fmaf(sc, pre, sh));
    }
    xout[(size_t)p * CC + o] = f2bf(fmaxf(mx, 0.0f));
}

// ---------------------------------------------------------------------------
// bf16 MFMA GEMM: out[m,o] = epilogue( dot(A[m,:K], W[o,:K]) )   (B^T layout)
// BM=64, BN=128, BK=64; 256 threads = 4 waves (2x2), each wave 32x64.
// global_load_lds(16B) into linear LDS with pre-swizzled global source;
// ds_read_b128 frag reads use byte^=(row&7)<<4 -> conflict-free.
// MODE 0: bf16 store          (T = feats @ WnF^T)
// MODE 1: bf16 relu(bn(z))    (h)
// MODE 2: f32 relu(bn(z)+res) (out)
// ---------------------------------------------------------------------------
template<int MODE>
__global__ __launch_bounds__(256, 2)
void mfma_gemm_kernel(const unsigned short* __restrict__ A, const unsigned short* __restrict__ W,
                      const float* __restrict__ g, const float* __restrict__ bb,
                      const float* __restrict__ mu, const float* __restrict__ var,
                      const float* __restrict__ res, void* __restrict__ outv,
                      int M, int Nout, int K)
{
    constexpr int BM = 64, BN = 128, BK = 64;
    __shared__ char smem[(BM + BN) * BK * 2];     // A: 8 KB, B: 16 KB
    char* sA = smem;
    char* sB = smem + BM * BK * 2;

    const int t    = threadIdx.x;
    const int lane = t & 63;
    const int w    = t >> 6;
    const int wm   = w >> 1;                      // 0..1
    const int wn   = w & 1;                       // 0..1
    const int m0   = blockIdx.x * BM;
    const int o0   = blockIdx.y * BN;
    const int Kb   = K * 2;

    f32x4 acc[2][4];
    #pragma unroll
    for (int i = 0; i < 2; ++i)
        #pragma unroll
        for (int j = 0; j < 4; ++j) acc[i][j] = f32x4{0.f, 0.f, 0.f, 0.f};

    const char* Ab = (const char*)A;
    const char* Wb = (const char*)W;

    for (int kc = 0; kc < K; kc += BK) {
        const int kcb = kc * 2;
        // A tile: 64 rows x 128 B; 8 wave-chunks of 1 KB (2 per wave)
        #pragma unroll
        for (int l = 0; l < 2; ++l) {
            const int q     = w * 2 + l;
            const int Lb    = q * 1024 + lane * 16;
            const int row   = Lb >> 7;
            const int inrow = Lb & 127;
            const char* src = Ab + (size_t)(m0 + row) * Kb + kcb + (inrow ^ ((row & 7) << 4));
            gload_lds16(src, sA + q * 1024);
        }
        // B tile: 128 rows x 128 B; 16 wave-chunks (4 per wave)
        #pragma unroll
        for (int l = 0; l < 4; ++l) {
            const int q     = w * 4 + l;
            const int Lb    = q * 1024 + lane * 16;
            const int row   = Lb >> 7;
            const int inrow = Lb & 127;
            const char* src = Wb + (size_t)(o0 + row) * Kb + kcb + (inrow ^ ((row & 7) << 4));
            gload_lds16(src, sB + q * 1024);
        }
        __syncthreads();

        #pragma unroll
        for (int ks = 0; ks < 2; ++ks) {
            const int kbyte = ks * 64 + (lane >> 4) * 16;
            bf16x8 af[2], bf[4];
            #pragma unroll
            for (int i = 0; i < 2; ++i) {
                const int r = wm * 32 + i * 16 + (lane & 15);
                af[i] = *(const bf16x8*)(sA + r * 128 + (kbyte ^ ((r & 7) << 4)));
            }
            #pragma unroll
            for (int j = 0; j < 4; ++j) {
                const int r = wn * 64 + j * 16 + (lane & 15);
                bf[j] = *(const bf16x8*)(sB + r * 128 + (kbyte ^ ((r & 7) << 4)));
            }
            #pragma unroll
            for (int i = 0; i < 2; ++i)
                #pragma unroll
                for (int j = 0; j < 4; ++j)
                    acc[i][j] = __builtin_amdgcn_mfma_f32_16x16x32_bf16(af[i], bf[j], acc[i][j], 0, 0, 0);
        }
        __syncthreads();
    }

    // epilogue: D layout col=lane&15, row=(lane>>4)*4+reg  [m89/m91 verified]
    #pragma unroll
    for (int j = 0; j < 4; ++j) {
        const int col = o0 + wn * 64 + j * 16 + (lane & 15);
        float scg = 1.f, sh = 0.f, mm = 0.f;
        if constexpr (MODE >= 1) {
            scg = g[col] / sqrtf(var[col] + EPSF);
            mm  = mu[col];
            sh  = bb[col];
        }
        #pragma unroll
        for (int i = 0; i < 2; ++i) {
            const int rowb = m0 + wm * 32 + i * 16 + (lane >> 4) * 4;
            #pragma unroll
            for (int r = 0; r < 4; ++r) {
                float z = acc[i][j][r];
                if constexpr (MODE >= 1) z = (z - mm) * scg + sh;
                if constexpr (MODE == 2) z += res[(size_t)(rowb + r) * Nout + col];
                if constexpr (MODE >= 1) z = fmaxf(z, 0.f);
                if constexpr (MODE == 2)
                    ((float*)outv)[(size_t)(rowb + r) * Nout + col] = z;
                else
                    ((unsigned short*)outv)[(size_t)(rowb + r) * Nout + col] = f2bf(z);
            }
        }
    }
}

// ---------------------------------------------------------------------------
extern "C" void kernel_launch(void* const* d_in, const int* in_sizes, int n_in,
                              void* d_out, int out_size, void* d_ws, size_t ws_size,
                              hipStream_t stream)
{
    const float* xyz   = (const float*)d_in[0];
    const float* feats = (const float*)d_in[1];
    const float* Wn    = (const float*)d_in[2];
    const float* gn    = (const float*)d_in[3];
    const float* bn_   = (const float*)d_in[4];
    const float* mn    = (const float*)d_in[5];
    const float* vn    = (const float*)d_in[6];
    const float* W1    = (const float*)d_in[7];
    const float* g1    = (const float*)d_in[8];
    const float* b1    = (const float*)d_in[9];
    const float* m1    = (const float*)d_in[10];
    const float* v1    = (const float*)d_in[11];
    const float* W2    = (const float*)d_in[12];
    const float* g2    = (const float*)d_in[13];
    const float* b2    = (const float*)d_in[14];
    const float* m2    = (const float*)d_in[15];
    const float* v2    = (const float*)d_in[16];
    float* out = (float*)d_out;

    // workspace layout (bytes)
    char* ws = (char*)d_ws;
    int*            idx    = (int*)(ws);                        // 2 MB
    unsigned short* WnF    = (unsigned short*)(ws +  2097152);  // 32 KB
    unsigned short* W1b    = (unsigned short*)(ws +  2129920);  // 128 KB
    unsigned short* W2b    = (unsigned short*)(ws +  2260992);  // 128 KB
    unsigned short* featsb = (unsigned short*)(ws +  2392064);  // 4 MB
    unsigned short* Tb     = (unsigned short*)(ws +  6586368);  // 4 MB
    unsigned short* xb     = (unsigned short*)(ws + 10780672);  // 4 MB
    unsigned short* hb     = (unsigned short*)(ws + 14974976);  // 16 MB -> ~30.3 MB total

    const int M = BB * NN;  // 16384

    pack_weights_kernel<<<576, 256, 0, stream>>>(Wn, W1, W2, WnF, W1b, W2b);
    convert_feats_kernel<<<2048, 256, 0, stream>>>(feats, featsb);
    ball_query_kernel<<<M, 64, 0, stream>>>(xyz, idx);

    // T = feats @ WnF^T   (M x 128, K=128) -> bf16
    mfma_gemm_kernel<0><<<dim3(M / 64, 1), 256, 0, stream>>>(
        featsb, WnF, nullptr, nullptr, nullptr, nullptr, nullptr, Tb, M, CC, CC);

    // x = relu(max_s bn1(T_gather + xyz-part)) -> bf16
    group_max_kernel<<<M, 128, 0, stream>>>(xyz, Tb, Wn, gn, bn_, mn, vn, idx, xb);

    // h = relu(bn1'(x @ W1^T))   (M x 512, K=128) -> bf16
    mfma_gemm_kernel<1><<<dim3(M / 64, HH / 128), 256, 0, stream>>>(
        xb, W1b, g1, b1, m1, v1, nullptr, hb, M, HH, CC);

    // out = relu(bn2(h @ W2^T) + feats)   (M x 128, K=512) -> f32
    mfma_gemm_kernel<2><<<dim3(M / 64, 1), 256, 0, stream>>>(
        hb, W2b, g2, b2, m2, v2, feats, out, M, CC, HH);
}

// Round 4
// 187.429 us; speedup vs baseline: 1.4679x; 1.1131x over previous
//
#include <hip/hip_runtime.h>
#include <hip/hip_bf16.h>
#include <math.h>

// Problem dims (fixed by setup_inputs): B=4, N=4096, C=128, H=512, S=32
static constexpr int BB = 4;
static constexpr int NN = 4096;
static constexpr int CC = 128;
static constexpr int HH = 512;
static constexpr int SS = 32;
static constexpr float EPSF = 1e-5f;
static constexpr int NCELL = 1000;            // 10x10x10 per batch

typedef __bf16 bf16_t;
typedef bf16_t bf16x8 __attribute__((ext_vector_type(8)));
typedef float f32x4 __attribute__((ext_vector_type(4)));

__device__ inline unsigned short f2bf(float f) {
    unsigned int u = __builtin_bit_cast(unsigned int, f);
    u += 0x7FFFu + ((u >> 16) & 1u);          // RNE
    return (unsigned short)(u >> 16);
}
__device__ inline float bf2f(unsigned short s) {
    unsigned int u = ((unsigned int)s) << 16;
    return __builtin_bit_cast(float, u);
}
__device__ inline int cell_of(float v) {
    int c = (int)(v * 10.0f);
    return c > 9 ? 9 : (c < 0 ? 0 : c);
}

__device__ inline void gload_lds16(const void* g, void* l) {
    __builtin_amdgcn_global_load_lds(
        (const __attribute__((address_space(1))) unsigned int*)g,
        (__attribute__((address_space(3))) unsigned int*)l, 16, 0, 0);
}

// ---------------------------------------------------------------------------
// Prep: pack weights to bf16, convert feats to bf16, zero cell counters.
// ---------------------------------------------------------------------------
__global__ __launch_bounds__(256)
void prep_kernel(const float* __restrict__ Wn, const float* __restrict__ W1,
                 const float* __restrict__ W2, const float* __restrict__ feats,
                 unsigned short* __restrict__ WnF, unsigned short* __restrict__ W1b,
                 unsigned short* __restrict__ W2b, unsigned short* __restrict__ featsb,
                 int* __restrict__ counts)
{
    const int blk = blockIdx.x;
    const int t   = threadIdx.x;
    if (blk < 576) {
        const int i = blk * 256 + t;
        if (i < 16384) {
            const int o = i >> 7, c = i & 127;
            WnF[i] = f2bf(Wn[o * 131 + 3 + c]);
        } else if (i < 16384 + 65536) {
            const int k = i - 16384;
            W1b[k] = f2bf(W1[k]);
        } else if (i < 16384 + 131072) {
            const int k = i - 16384 - 65536;
            W2b[k] = f2bf(W2[k]);
        }
    } else if (blk < 2624) {
        const int i = (blk - 576) * 256 + t;      // float4 id
        const float4 v = ((const float4*)feats)[i];
        unsigned long long pk = (unsigned long long)f2bf(v.x)
                              | ((unsigned long long)f2bf(v.y) << 16)
                              | ((unsigned long long)f2bf(v.z) << 32)
                              | ((unsigned long long)f2bf(v.w) << 48);
        ((unsigned long long*)featsb)[i] = pk;
    } else {
        const int i = (blk - 2624) * 256 + t;
        if (i < BB * NCELL) counts[i] = 0;
    }
}

// ---------------------------------------------------------------------------
// Histogram points into cells.
// ---------------------------------------------------------------------------
__global__ __launch_bounds__(256)
void count_kernel(const float* __restrict__ xyz, int* __restrict__ counts)
{
    const int p = blockIdx.x * 256 + threadIdx.x;   // 0..16383
    const int b = p >> 12;
    const float x = xyz[p * 3 + 0], y = xyz[p * 3 + 1], z = xyz[p * 3 + 2];
    const int cid = cell_of(z) * 100 + cell_of(y) * 10 + cell_of(x);
    atomicAdd(&counts[b * NCELL + cid], 1);
}

// ---------------------------------------------------------------------------
// One-block exclusive scan over 4000 counts -> starts[4001]; cursor = starts.
// ---------------------------------------------------------------------------
__global__ __launch_bounds__(1024)
void scan_kernel(const int* __restrict__ counts, int* __restrict__ starts,
                 int* __restrict__ cursor)
{
    const int t  = threadIdx.x;
    const int i0 = t * 4;
    int v[4];
    #pragma unroll
    for (int k = 0; k < 4; ++k)
        v[k] = (i0 + k < BB * NCELL) ? counts[i0 + k] : 0;
    const int s = v[0] + v[1] + v[2] + v[3];

    __shared__ int ls[1024];
    ls[t] = s;
    __syncthreads();
    #pragma unroll
    for (int off = 1; off < 1024; off <<= 1) {
        const int add = (t >= off) ? ls[t - off] : 0;
        __syncthreads();
        ls[t] += add;
        __syncthreads();
    }
    int ex = ls[t] - s;                       // exclusive prefix of this thread
    #pragma unroll
    for (int k = 0; k < 4; ++k) {
        if (i0 + k < BB * NCELL) {
            starts[i0 + k] = ex;
            cursor[i0 + k] = ex;
        }
        ex += v[k];
    }
    if (t == 1023) starts[BB * NCELL] = ls[1023];
}

// ---------------------------------------------------------------------------
// Scatter points cell-sorted: spts[pos] = {x, y, z, bitcast(local_n)}
// ---------------------------------------------------------------------------
__global__ __launch_bounds__(256)
void scatter_kernel(const float* __restrict__ xyz, int* __restrict__ cursor,
                    float4* __restrict__ spts)
{
    const int p = blockIdx.x * 256 + threadIdx.x;
    const int b = p >> 12;
    const int n = p & (NN - 1);
    const float x = xyz[p * 3 + 0], y = xyz[p * 3 + 1], z = xyz[p * 3 + 2];
    const int cid = cell_of(z) * 100 + cell_of(y) * 10 + cell_of(x);
    const int pos = atomicAdd(&cursor[b * NCELL + cid], 1);
    spts[pos] = make_float4(x, y, z, __int_as_float(n));
}

// ---------------------------------------------------------------------------
// Binned ball query: one wave per query; 9 contiguous candidate ranges
// (x-cells contiguous); ballot-compact in-radius into LDS; rank-select the
// 32 smallest indices (== reference sort semantics).
// ---------------------------------------------------------------------------
__global__ __launch_bounds__(64)
void ball_query_binned_kernel(const float* __restrict__ xyz,
                              const int* __restrict__ starts,
                              const float4* __restrict__ spts,
                              int* __restrict__ idx)
{
    const int p    = blockIdx.x;
    const int b    = p >> 12;
    const int lane = threadIdx.x;

    const float qx = xyz[p * 3 + 0];
    const float qy = xyz[p * 3 + 1];
    const float qz = xyz[p * 3 + 2];
    const int cx = cell_of(qx), cy = cell_of(qy), cz = cell_of(qz);
    const int xlo = cx > 0 ? cx - 1 : 0;
    const int xhi = cx < 9 ? cx + 1 : 9;

    __shared__ int list[128];
    __shared__ int res[SS];
    int cnt = 0;

    for (int dz = -1; dz <= 1; ++dz) {
        const int z2 = cz + dz;
        if (z2 < 0 || z2 > 9) continue;
        for (int dy = -1; dy <= 1; ++dy) {
            const int y2 = cy + dy;
            if (y2 < 0 || y2 > 9) continue;
            const int base = b * NCELL + z2 * 100 + y2 * 10;
            const int lo = starts[base + xlo];
            const int hi = starts[base + xhi + 1];
            for (int j0 = lo; j0 < hi; j0 += 64) {
                const int j = j0 + lane;
                bool in = false;
                int pi = 0;
                if (j < hi) {
                    const float4 s = spts[j];
                    float sq;
                    {
                        #pragma clang fp contract(off)   // match numpy at boundary
                        const float dx  = qx - s.x;
                        const float dyv = qy - s.y;
                        const float dzv = qz - s.z;
                        sq = dx * dx + dyv * dyv + dzv * dzv;
                    }
                    in = (sq <= 0.01f);
                    pi = __float_as_int(s.w);
                }
                const unsigned long long mask = __ballot(in);
                if (in) {
                    const int pos = cnt + __popcll(mask & ((1ull << lane) - 1ull));
                    if (pos < 128) list[pos] = pi;
                }
                cnt += (int)__popcll(mask);
            }
        }
    }
    __syncthreads();

    const int c = cnt < 128 ? cnt : 128;      // c >= 1 (self always in-radius)
    #pragma unroll
    for (int l0 = 0; l0 < 2; ++l0) {
        const int l = lane + l0 * 64;
        if (l < c) {
            const int v = list[l];
            int r = 0;
            for (int k = 0; k < c; ++k) r += (list[k] < v);
            if (r < SS) res[r] = v;
        }
    }
    __syncthreads();

    if (lane < SS) {
        const int m = c < SS ? c : SS;
        idx[(size_t)p * SS + lane] = (lane < m) ? res[lane] : res[0];
    }
}

// ---------------------------------------------------------------------------
// Stage 1 fused: x[p,o] = relu( max_s bn1( T[b,idx_s,o] + Wn[o,0:3].gxyz_s ) )
// ---------------------------------------------------------------------------
__global__ __launch_bounds__(128)
void group_max_kernel(const float* __restrict__ xyz, const unsigned short* __restrict__ T,
                      const float* __restrict__ Wn,
                      const float* __restrict__ gn, const float* __restrict__ bnv,
                      const float* __restrict__ mn, const float* __restrict__ vn,
                      const int* __restrict__ idx, unsigned short* __restrict__ xout)
{
    const int p = blockIdx.x;
    const int b = p >> 12;
    const int o = threadIdx.x;

    __shared__ int   sj[SS];
    __shared__ float sgx[SS][3];

    const float* xb = xyz + (size_t)b * NN * 3;
    const float* q  = xyz + (size_t)p * 3;

    if (o < SS) {
        const int j = idx[(size_t)p * SS + o];
        sj[o] = j;
        sgx[o][0] = (xb[j * 3 + 0] - q[0]) / 0.1f;
        sgx[o][1] = (xb[j * 3 + 1] - q[1]) / 0.1f;
        sgx[o][2] = (xb[j * 3 + 2] - q[2]) / 0.1f;
    }
    __syncthreads();

    const float w0 = Wn[o * 131 + 0];
    const float w1 = Wn[o * 131 + 1];
    const float w2 = Wn[o * 131 + 2];
    const float sc = gn[o] / sqrtf(vn[o] + EPSF);
    const float sh = bnv[o] - mn[o] * sc;

    const unsigned short* Tb = T + (size_t)b * NN * CC;
    float mx = -INFINITY;
    #pragma unroll 8
    for (int s = 0; s < SS; ++s) {
        const float pre = bf2f(Tb[(size_t)sj[s] * CC + o])
                        + w0 * sgx[s][0] + w1 * sgx[s][1] + w2 * sgx[s][2];
        mx = fmaxf(mx, fmaf(sc, pre, sh));
    }
    xout[(size_t)p * CC + o] = f2bf(fmaxf(mx, 0.0f));
}

// ---------------------------------------------------------------------------
// bf16 MFMA GEMM (B^T): BM=64, BN=128, BK=64; 4 waves (2x2), wave 32x64.
// global_load_lds(16B) -> linear LDS, pre-swizzled source; swizzled ds_read.
// MODE 0: bf16 store; MODE 1: bf16 relu(bn); MODE 2: f32 relu(bn + res).
// ---------------------------------------------------------------------------
template<int MODE>
__global__ __launch_bounds__(256, 2)
void mfma_gemm_kernel(const unsigned short* __restrict__ A, const unsigned short* __restrict__ W,
                      const float* __restrict__ g, const float* __restrict__ bb,
                      const float* __restrict__ mu, const float* __restrict__ var,
                      const float* __restrict__ res, void* __restrict__ outv,
                      int M, int Nout, int K)
{
    constexpr int BM = 64, BN = 128, BK = 64;
    __shared__ char smem[(BM + BN) * BK * 2];
    char* sA = smem;
    char* sB = smem + BM * BK * 2;

    const int t    = threadIdx.x;
    const int lane = t & 63;
    const int w    = t >> 6;
    const int wm   = w >> 1;
    const int wn   = w & 1;
    const int m0   = blockIdx.x * BM;
    const int o0   = blockIdx.y * BN;
    const int Kb   = K * 2;

    f32x4 acc[2][4];
    #pragma unroll
    for (int i = 0; i < 2; ++i)
        #pragma unroll
        for (int j = 0; j < 4; ++j) acc[i][j] = f32x4{0.f, 0.f, 0.f, 0.f};

    const char* Ab = (const char*)A;
    const char* Wb = (const char*)W;

    for (int kc = 0; kc < K; kc += BK) {
        const int kcb = kc * 2;
        #pragma unroll
        for (int l = 0; l < 2; ++l) {
            const int q     = w * 2 + l;
            const int Lb    = q * 1024 + lane * 16;
            const int row   = Lb >> 7;
            const int inrow = Lb & 127;
            const char* src = Ab + (size_t)(m0 + row) * Kb + kcb + (inrow ^ ((row & 7) << 4));
            gload_lds16(src, sA + q * 1024);
        }
        #pragma unroll
        for (int l = 0; l < 4; ++l) {
            const int q     = w * 4 + l;
            const int Lb    = q * 1024 + lane * 16;
            const int row   = Lb >> 7;
            const int inrow = Lb & 127;
            const char* src = Wb + (size_t)(o0 + row) * Kb + kcb + (inrow ^ ((row & 7) << 4));
            gload_lds16(src, sB + q * 1024);
        }
        __syncthreads();

        #pragma unroll
        for (int ks = 0; ks < 2; ++ks) {
            const int kbyte = ks * 64 + (lane >> 4) * 16;
            bf16x8 af[2], bf[4];
            #pragma unroll
            for (int i = 0; i < 2; ++i) {
                const int r = wm * 32 + i * 16 + (lane & 15);
                af[i] = *(const bf16x8*)(sA + r * 128 + (kbyte ^ ((r & 7) << 4)));
            }
            #pragma unroll
            for (int j = 0; j < 4; ++j) {
                const int r = wn * 64 + j * 16 + (lane & 15);
                bf[j] = *(const bf16x8*)(sB + r * 128 + (kbyte ^ ((r & 7) << 4)));
            }
            #pragma unroll
            for (int i = 0; i < 2; ++i)
                #pragma unroll
                for (int j = 0; j < 4; ++j)
                    acc[i][j] = __builtin_amdgcn_mfma_f32_16x16x32_bf16(af[i], bf[j], acc[i][j], 0, 0, 0);
        }
        __syncthreads();
    }

    #pragma unroll
    for (int j = 0; j < 4; ++j) {
        const int col = o0 + wn * 64 + j * 16 + (lane & 15);
        float scg = 1.f, sh = 0.f, mm = 0.f;
        if constexpr (MODE >= 1) {
            scg = g[col] / sqrtf(var[col] + EPSF);
            mm  = mu[col];
            sh  = bb[col];
        }
        #pragma unroll
        for (int i = 0; i < 2; ++i) {
            const int rowb = m0 + wm * 32 + i * 16 + (lane >> 4) * 4;
            #pragma unroll
            for (int r = 0; r < 4; ++r) {
                float z = acc[i][j][r];
                if constexpr (MODE >= 1) z = (z - mm) * scg + sh;
                if constexpr (MODE == 2) z += res[(size_t)(rowb + r) * Nout + col];
                if constexpr (MODE >= 1) z = fmaxf(z, 0.f);
                if constexpr (MODE == 2)
                    ((float*)outv)[(size_t)(rowb + r) * Nout + col] = z;
                else
                    ((unsigned short*)outv)[(size_t)(rowb + r) * Nout + col] = f2bf(z);
            }
        }
    }
}

// ---------------------------------------------------------------------------
extern "C" void kernel_launch(void* const* d_in, const int* in_sizes, int n_in,
                              void* d_out, int out_size, void* d_ws, size_t ws_size,
                              hipStream_t stream)
{
    const float* xyz   = (const float*)d_in[0];
    const float* feats = (const float*)d_in[1];
    const float* Wn    = (const float*)d_in[2];
    const float* gn    = (const float*)d_in[3];
    const float* bn_   = (const float*)d_in[4];
    const float* mn    = (const float*)d_in[5];
    const float* vn    = (const float*)d_in[6];
    const float* W1    = (const float*)d_in[7];
    const float* g1    = (const float*)d_in[8];
    const float* b1    = (const float*)d_in[9];
    const float* m1    = (const float*)d_in[10];
    const float* v1    = (const float*)d_in[11];
    const float* W2    = (const float*)d_in[12];
    const float* g2    = (const float*)d_in[13];
    const float* b2    = (const float*)d_in[14];
    const float* m2    = (const float*)d_in[15];
    const float* v2    = (const float*)d_in[16];
    float* out = (float*)d_out;

    // workspace layout (bytes)
    char* ws = (char*)d_ws;
    int*            idx    = (int*)(ws);                        // 2 MB
    int*            counts = (int*)(ws + 2097152);              // 16 KB
    int*            starts = (int*)(ws + 2113536);              // 16 KB
    int*            cursor = (int*)(ws + 2129920);              // 16 KB
    float4*         spts   = (float4*)(ws + 2146304);           // 256 KB
    unsigned short* WnF    = (unsigned short*)(ws +  2408448);  // 32 KB
    unsigned short* W1b    = (unsigned short*)(ws +  2441216);  // 128 KB
    unsigned short* W2b    = (unsigned short*)(ws +  2572288);  // 128 KB
    unsigned short* featsb = (unsigned short*)(ws +  2703360);  // 4 MB
    unsigned short* Tb     = (unsigned short*)(ws +  6897664);  // 4 MB
    unsigned short* xb     = (unsigned short*)(ws + 11091968);  // 4 MB
    unsigned short* hb     = (unsigned short*)(ws + 15286272);  // 16 MB (~30.6 MB total)

    const int M = BB * NN;  // 16384

    prep_kernel<<<2640, 256, 0, stream>>>(Wn, W1, W2, feats, WnF, W1b, W2b, featsb, counts);
    count_kernel<<<64, 256, 0, stream>>>(xyz, counts);
    scan_kernel<<<1, 1024, 0, stream>>>(counts, starts, cursor);
    scatter_kernel<<<64, 256, 0, stream>>>(xyz, cursor, spts);
    ball_query_binned_kernel<<<M, 64, 0, stream>>>(xyz, starts, spts, idx);

    // T = feats @ WnF^T   (M x 128, K=128) -> bf16
    mfma_gemm_kernel<0><<<dim3(M / 64, 1), 256, 0, stream>>>(
        featsb, WnF, nullptr, nullptr, nullptr, nullptr, nullptr, Tb, M, CC, CC);

    // x = relu(max_s bn1(T_gather + xyz-part)) -> bf16
    group_max_kernel<<<M, 128, 0, stream>>>(xyz, Tb, Wn, gn, bn_, mn, vn, idx, xb);

    // h = relu(bn1'(x @ W1^T))   (M x 512, K=128) -> bf16
    mfma_gemm_kernel<1><<<dim3(M / 64, HH / 128), 256, 0, stream>>>(
        xb, W1b, g1, b1, m1, v1, nullptr, hb, M, HH, CC);

    // out = relu(bn2(h @ W2^T) + feats)   (M x 512, K=512) -> f32
    mfma_gemm_kernel<2><<<dim3(M / 64, 1), 256, 0, stream>>>(
        hb, W2b, g2, b2, m2, v2, feats, out, M, CC, HH);
}

// Round 8
// 159.089 us; speedup vs baseline: 1.7294x; 1.1781x over previous
//
#include <hip/hip_runtime.h>
#include <hip/hip_bf16.h>
#include <math.h>

// Problem dims (fixed by setup_inputs): B=4, N=4096, C=128, H=512, S=32
static constexpr int BB = 4;
static constexpr int NN = 4096;
static constexpr int CC = 128;
static constexpr int HH = 512;
static constexpr int SS = 32;
static constexpr float EPSF = 1e-5f;
static constexpr int NCELL = 1000;            // 10x10x10 per batch

typedef __bf16 bf16_t;
typedef bf16_t bf16x8 __attribute__((ext_vector_type(8)));
typedef float f32x4 __attribute__((ext_vector_type(4)));
typedef float f32x2 __attribute__((ext_vector_type(2)));

__device__ inline unsigned short f2bf(float f) {
    unsigned int u = __builtin_bit_cast(unsigned int, f);
    u += 0x7FFFu + ((u >> 16) & 1u);          // RNE
    return (unsigned short)(u >> 16);
}
__device__ inline float bf2f(unsigned short s) {
    unsigned int u = ((unsigned int)s) << 16;
    return __builtin_bit_cast(float, u);
}
__device__ inline float u2f(unsigned int u) {
    return __builtin_bit_cast(float, u);
}
__device__ inline int cell_of(float v) {
    int c = (int)(v * 10.0f);
    return c > 9 ? 9 : (c < 0 ? 0 : c);
}
// packed fp32 fma with scalar broadcast: D = a * {g,g} + c
// (plain vector expr -> LLVM contracts to v_pk_fma_f32 on gfx950; the {g,g}
//  splat is one v_mov and is CSE'd across calls sharing g)
__device__ inline f32x2 pk_fma_b(f32x2 a, float g, f32x2 c) {
    const f32x2 gg = {g, g};
    return a * gg + c;
}

__device__ inline void gload_lds16(const void* g, void* l) {
    __builtin_amdgcn_global_load_lds(
        (const __attribute__((address_space(1))) unsigned int*)g,
        (__attribute__((address_space(3))) unsigned int*)l, 16, 0, 0);
}

// ---------------------------------------------------------------------------
// Prep: pack weights to bf16, convert feats to bf16, zero counters, wfold.
// ---------------------------------------------------------------------------
__global__ __launch_bounds__(256)
void prep_kernel(const float* __restrict__ Wn, const float* __restrict__ W1,
                 const float* __restrict__ W2, const float* __restrict__ feats,
                 const float* __restrict__ gn, const float* __restrict__ bnv,
                 const float* __restrict__ mn, const float* __restrict__ vn,
                 unsigned short* __restrict__ WnF, unsigned short* __restrict__ W1b,
                 unsigned short* __restrict__ W2b, unsigned short* __restrict__ featsb,
                 int* __restrict__ counts, float4* __restrict__ wfold)
{
    const int blk = blockIdx.x;
    const int t   = threadIdx.x;
    if (blk < 576) {
        const int i = blk * 256 + t;
        if (i < 16384) {
            const int o = i >> 7, c = i & 127;
            WnF[i] = f2bf(Wn[o * 131 + 3 + c]);
        } else if (i < 16384 + 65536) {
            const int k = i - 16384;
            W1b[k] = f2bf(W1[k]);
        } else if (i < 16384 + 131072) {
            const int k = i - 16384 - 65536;
            W2b[k] = f2bf(W2[k]);
        }
    } else if (blk < 2624) {
        const int i = (blk - 576) * 256 + t;      // float4 id
        const float4 v = ((const float4*)feats)[i];
        unsigned long long pk = (unsigned long long)f2bf(v.x)
                              | ((unsigned long long)f2bf(v.y) << 16)
                              | ((unsigned long long)f2bf(v.z) << 32)
                              | ((unsigned long long)f2bf(v.w) << 48);
        ((unsigned long long*)featsb)[i] = pk;
    } else if (blk < 2640) {
        const int i = (blk - 2624) * 256 + t;
        if (i < BB * NCELL) counts[i] = 0;
    } else {
        // wfold[o] = {sc*w0, sc*w1, sc*w2, sh};  sc = gn/sqrt(vn+eps), sh = bnv - mn*sc
        if (t < CC) {
            const float sc = gn[t] / sqrtf(vn[t] + EPSF);
            wfold[t] = make_float4(sc * Wn[t * 131 + 0], sc * Wn[t * 131 + 1],
                                   sc * Wn[t * 131 + 2], bnv[t] - mn[t] * sc);
        }
    }
}

// ---------------------------------------------------------------------------
// Histogram points into cells.
// ---------------------------------------------------------------------------
__global__ __launch_bounds__(256)
void count_kernel(const float* __restrict__ xyz, int* __restrict__ counts)
{
    const int p = blockIdx.x * 256 + threadIdx.x;   // 0..16383
    const int b = p >> 12;
    const float x = xyz[p * 3 + 0], y = xyz[p * 3 + 1], z = xyz[p * 3 + 2];
    const int cid = cell_of(z) * 100 + cell_of(y) * 10 + cell_of(x);
    atomicAdd(&counts[b * NCELL + cid], 1);
}

// ---------------------------------------------------------------------------
// One-block exclusive scan over 4000 counts -> starts[4001]; cursor = starts.
// ---------------------------------------------------------------------------
__global__ __launch_bounds__(1024)
void scan_kernel(const int* __restrict__ counts, int* __restrict__ starts,
                 int* __restrict__ cursor)
{
    const int t  = threadIdx.x;
    const int i0 = t * 4;
    int v[4];
    #pragma unroll
    for (int k = 0; k < 4; ++k)
        v[k] = (i0 + k < BB * NCELL) ? counts[i0 + k] : 0;
    const int s = v[0] + v[1] + v[2] + v[3];

    __shared__ int ls[1024];
    ls[t] = s;
    __syncthreads();
    #pragma unroll
    for (int off = 1; off < 1024; off <<= 1) {
        const int add = (t >= off) ? ls[t - off] : 0;
        __syncthreads();
        ls[t] += add;
        __syncthreads();
    }
    int ex = ls[t] - s;                       // exclusive prefix of this thread
    #pragma unroll
    for (int k = 0; k < 4; ++k) {
        if (i0 + k < BB * NCELL) {
            starts[i0 + k] = ex;
            cursor[i0 + k] = ex;
        }
        ex += v[k];
    }
    if (t == 1023) starts[BB * NCELL] = ls[1023];
}

// ---------------------------------------------------------------------------
// Scatter points cell-sorted: spts[pos] = {x, y, z, bitcast(local_n)}
// ---------------------------------------------------------------------------
__global__ __launch_bounds__(256)
void scatter_kernel(const float* __restrict__ xyz, int* __restrict__ cursor,
                    float4* __restrict__ spts)
{
    const int p = blockIdx.x * 256 + threadIdx.x;
    const int b = p >> 12;
    const int n = p & (NN - 1);
    const float x = xyz[p * 3 + 0], y = xyz[p * 3 + 1], z = xyz[p * 3 + 2];
    const int cid = cell_of(z) * 100 + cell_of(y) * 10 + cell_of(x);
    const int pos = atomicAdd(&cursor[b * NCELL + cid], 1);
    spts[pos] = make_float4(x, y, z, __int_as_float(n));
}

// ---------------------------------------------------------------------------
// Binned ball query: one wave per query; 9 contiguous candidate ranges;
// ballot-compact in-radius; rank-select the 32 smallest indices.
// ---------------------------------------------------------------------------
__global__ __launch_bounds__(64)
void ball_query_binned_kernel(const float* __restrict__ xyz,
                              const int* __restrict__ starts,
                              const float4* __restrict__ spts,
                              int* __restrict__ idx)
{
    const int p    = blockIdx.x;
    const int b    = p >> 12;
    const int lane = threadIdx.x;

    const float qx = xyz[p * 3 + 0];
    const float qy = xyz[p * 3 + 1];
    const float qz = xyz[p * 3 + 2];
    const int cx = cell_of(qx), cy = cell_of(qy), cz = cell_of(qz);
    const int xlo = cx > 0 ? cx - 1 : 0;
    const int xhi = cx < 9 ? cx + 1 : 9;

    __shared__ int list[128];
    __shared__ int res[SS];
    int cnt = 0;

    for (int dz = -1; dz <= 1; ++dz) {
        const int z2 = cz + dz;
        if (z2 < 0 || z2 > 9) continue;
        for (int dy = -1; dy <= 1; ++dy) {
            const int y2 = cy + dy;
            if (y2 < 0 || y2 > 9) continue;
            const int base = b * NCELL + z2 * 100 + y2 * 10;
            const int lo = starts[base + xlo];
            const int hi = starts[base + xhi + 1];
            for (int j0 = lo; j0 < hi; j0 += 64) {
                const int j = j0 + lane;
                bool in = false;
                int pi = 0;
                if (j < hi) {
                    const float4 s = spts[j];
                    float sq;
                    {
                        #pragma clang fp contract(off)   // match numpy at boundary
                        const float dx  = qx - s.x;
                        const float dyv = qy - s.y;
                        const float dzv = qz - s.z;
                        sq = dx * dx + dyv * dyv + dzv * dzv;
                    }
                    in = (sq <= 0.01f);
                    pi = __float_as_int(s.w);
                }
                const unsigned long long mask = __ballot(in);
                if (in) {
                    const int pos = cnt + __popcll(mask & ((1ull << lane) - 1ull));
                    if (pos < 128) list[pos] = pi;
                }
                cnt += (int)__popcll(mask);
            }
        }
    }
    __syncthreads();

    const int c = cnt < 128 ? cnt : 128;      // c >= 1 (self always in-radius)
    #pragma unroll
    for (int l0 = 0; l0 < 2; ++l0) {
        const int l = lane + l0 * 64;
        if (l < c) {
            const int v = list[l];
            int r = 0;
            for (int k = 0; k < c; ++k) r += (list[k] < v);
            if (r < SS) res[r] = v;
        }
    }
    __syncthreads();

    if (lane < SS) {
        const int m = c < SS ? c : SS;
        idx[(size_t)p * SS + lane] = (lane < m) ? res[lane] : res[0];
    }
}

// ---------------------------------------------------------------------------
// Stage 1 fused (v2): x[p,o] = relu( max_s ( T'[j_s,o] + w'[o]·gxyz_s ) + sh[o] )
// where T' = sc*T (scaled in GEMM epilogue), w' = sc*w, sh folded post-max.
// Block 256 thr = 8 points; 32 lanes/point, 4 channels/thread, packed fp32 fma.
// ---------------------------------------------------------------------------
__global__ __launch_bounds__(256)
void group_max_kernel(const float* __restrict__ xyz,
                      const unsigned short* __restrict__ T,   // pre-scaled bf16
                      const float4* __restrict__ wfold,
                      const int* __restrict__ idx, unsigned short* __restrict__ xout)
{
    const int t   = threadIdx.x;
    const int ptl = t >> 5;                    // 0..7 local point
    const int l   = t & 31;                    // lane within point
    const int p   = blockIdx.x * 8 + ptl;
    const int b   = p >> 12;

    __shared__ float4 sg[8][32];               // {gx, gy, gz, bitcast(j)}

    {   // setup: thread (ptl, l) handles sample s = l of its point
        const int j = idx[(size_t)p * SS + l];
        const float* q  = xyz + (size_t)p * 3;
        const float* pj = xyz + ((size_t)b * NN + j) * 3;
        sg[ptl][l] = make_float4((pj[0] - q[0]) / 0.1f,
                                 (pj[1] - q[1]) / 0.1f,
                                 (pj[2] - q[2]) / 0.1f, __int_as_float(j));
    }
    __syncthreads();

    const int c0 = l * 4;                      // this thread's 4 channels
    const float4 wa = wfold[c0 + 0], wb = wfold[c0 + 1];
    const float4 wc = wfold[c0 + 2], wd = wfold[c0 + 3];
    const f32x2 w0p0 = {wa.x, wb.x}, w1p0 = {wa.y, wb.y}, w2p0 = {wa.z, wb.z};
    const f32x2 w0p1 = {wc.x, wd.x}, w1p1 = {wc.y, wd.y}, w2p1 = {wc.z, wd.z};

    const unsigned short* Tb = T + (size_t)b * NN * CC;
    f32x2 mx0 = {-1e30f, -1e30f}, mx1 = {-1e30f, -1e30f};

    #pragma unroll 8
    for (int s = 0; s < SS; ++s) {
        const float4 g = sg[ptl][s];
        const int j = __float_as_int(g.w);
        const uint2 tv = *(const uint2*)(Tb + (size_t)j * CC + c0);
        f32x2 v0, v1;
        v0.x = u2f(tv.x << 16); v0.y = u2f(tv.x & 0xFFFF0000u);
        v1.x = u2f(tv.y << 16); v1.y = u2f(tv.y & 0xFFFF0000u);
        v0 = pk_fma_b(w0p0, g.x, v0); v0 = pk_fma_b(w1p0, g.y, v0); v0 = pk_fma_b(w2p0, g.z, v0);
        v1 = pk_fma_b(w0p1, g.x, v1); v1 = pk_fma_b(w1p1, g.y, v1); v1 = pk_fma_b(w2p1, g.z, v1);
        mx0.x = fmaxf(mx0.x, v0.x); mx0.y = fmaxf(mx0.y, v0.y);
        mx1.x = fmaxf(mx1.x, v1.x); mx1.y = fmaxf(mx1.y, v1.y);
    }

    const float r0 = fmaxf(mx0.x + wa.w, 0.f);
    const float r1 = fmaxf(mx0.y + wb.w, 0.f);
    const float r2 = fmaxf(mx1.x + wc.w, 0.f);
    const float r3 = fmaxf(mx1.y + wd.w, 0.f);
    uint2 o;
    o.x = (unsigned)f2bf(r0) | ((unsigned)f2bf(r1) << 16);
    o.y = (unsigned)f2bf(r2) | ((unsigned)f2bf(r3) << 16);
    *(uint2*)(xout + (size_t)p * CC + c0) = o;
}

// ---------------------------------------------------------------------------
// bf16 MFMA GEMM (B^T): BM=64, BN=128, BK=64; 4 waves (2x2), wave 32x64.
// MODE 1: bf16 relu(bn); MODE 2: f32 relu(bn + res); MODE 3: bf16 sc*z.
// ---------------------------------------------------------------------------
template<int MODE>
__global__ __launch_bounds__(256, 2)
void mfma_gemm_kernel(const unsigned short* __restrict__ A, const unsigned short* __restrict__ W,
                      const float* __restrict__ g, const float* __restrict__ bb,
                      const float* __restrict__ mu, const float* __restrict__ var,
                      const float* __restrict__ res, void* __restrict__ outv,
                      int M, int Nout, int K)
{
    constexpr int BM = 64, BN = 128, BK = 64;
    __shared__ char smem[(BM + BN) * BK * 2];
    char* sA = smem;
    char* sB = smem + BM * BK * 2;

    const int t    = threadIdx.x;
    const int lane = t & 63;
    const int w    = t >> 6;
    const int wm   = w >> 1;
    const int wn   = w & 1;
    const int m0   = blockIdx.x * BM;
    const int o0   = blockIdx.y * BN;
    const int Kb   = K * 2;

    f32x4 acc[2][4];
    #pragma unroll
    for (int i = 0; i < 2; ++i)
        #pragma unroll
        for (int j = 0; j < 4; ++j) acc[i][j] = f32x4{0.f, 0.f, 0.f, 0.f};

    const char* Ab = (const char*)A;
    const char* Wb = (const char*)W;

    for (int kc = 0; kc < K; kc += BK) {
        const int kcb = kc * 2;
        #pragma unroll
        for (int l = 0; l < 2; ++l) {
            const int q     = w * 2 + l;
            const int Lb    = q * 1024 + lane * 16;
            const int row   = Lb >> 7;
            const int inrow = Lb & 127;
            const char* src = Ab + (size_t)(m0 + row) * Kb + kcb + (inrow ^ ((row & 7) << 4));
            gload_lds16(src, sA + q * 1024);
        }
        #pragma unroll
        for (int l = 0; l < 4; ++l) {
            const int q     = w * 4 + l;
            const int Lb    = q * 1024 + lane * 16;
            const int row   = Lb >> 7;
            const int inrow = Lb & 127;
            const char* src = Wb + (size_t)(o0 + row) * Kb + kcb + (inrow ^ ((row & 7) << 4));
            gload_lds16(src, sB + q * 1024);
        }
        __syncthreads();

        #pragma unroll
        for (int ks = 0; ks < 2; ++ks) {
            const int kbyte = ks * 64 + (lane >> 4) * 16;
            bf16x8 af[2], bf[4];
            #pragma unroll
            for (int i = 0; i < 2; ++i) {
                const int r = wm * 32 + i * 16 + (lane & 15);
                af[i] = *(const bf16x8*)(sA + r * 128 + (kbyte ^ ((r & 7) << 4)));
            }
            #pragma unroll
            for (int j = 0; j < 4; ++j) {
                const int r = wn * 64 + j * 16 + (lane & 15);
                bf[j] = *(const bf16x8*)(sB + r * 128 + (kbyte ^ ((r & 7) << 4)));
            }
            #pragma unroll
            for (int i = 0; i < 2; ++i)
                #pragma unroll
                for (int j = 0; j < 4; ++j)
                    acc[i][j] = __builtin_amdgcn_mfma_f32_16x16x32_bf16(af[i], bf[j], acc[i][j], 0, 0, 0);
        }
        __syncthreads();
    }

    #pragma unroll
    for (int j = 0; j < 4; ++j) {
        const int col = o0 + wn * 64 + j * 16 + (lane & 15);
        float scg = 1.f, sh = 0.f, mm = 0.f;
        if constexpr (MODE == 1 || MODE == 2) {
            scg = g[col] / sqrtf(var[col] + EPSF);
            mm  = mu[col];
            sh  = bb[col];
        }
        if constexpr (MODE == 3) {
            scg = g[col] / sqrtf(var[col] + EPSF);
        }
        #pragma unroll
        for (int i = 0; i < 2; ++i) {
            const int rowb = m0 + wm * 32 + i * 16 + (lane >> 4) * 4;
            #pragma unroll
            for (int r = 0; r < 4; ++r) {
                float z = acc[i][j][r];
                if constexpr (MODE == 1 || MODE == 2) z = (z - mm) * scg + sh;
                if constexpr (MODE == 3) z = z * scg;
                if constexpr (MODE == 2) z += res[(size_t)(rowb + r) * Nout + col];
                if constexpr (MODE == 1 || MODE == 2) z = fmaxf(z, 0.f);
                if constexpr (MODE == 2)
                    ((float*)outv)[(size_t)(rowb + r) * Nout + col] = z;
                else
                    ((unsigned short*)outv)[(size_t)(rowb + r) * Nout + col] = f2bf(z);
            }
        }
    }
}

// ---------------------------------------------------------------------------
extern "C" void kernel_launch(void* const* d_in, const int* in_sizes, int n_in,
                              void* d_out, int out_size, void* d_ws, size_t ws_size,
                              hipStream_t stream)
{
    const float* xyz   = (const float*)d_in[0];
    const float* feats = (const float*)d_in[1];
    const float* Wn    = (const float*)d_in[2];
    const float* gn    = (const float*)d_in[3];
    const float* bn_   = (const float*)d_in[4];
    const float* mn    = (const float*)d_in[5];
    const float* vn    = (const float*)d_in[6];
    const float* W1    = (const float*)d_in[7];
    const float* g1    = (const float*)d_in[8];
    const float* b1    = (const float*)d_in[9];
    const float* m1    = (const float*)d_in[10];
    const float* v1    = (const float*)d_in[11];
    const float* W2    = (const float*)d_in[12];
    const float* g2    = (const float*)d_in[13];
    const float* b2    = (const float*)d_in[14];
    const float* m2    = (const float*)d_in[15];
    const float* v2    = (const float*)d_in[16];
    float* out = (float*)d_out;

    // workspace layout (bytes)
    char* ws = (char*)d_ws;
    int*            idx    = (int*)(ws);                        // 2 MB
    int*            counts = (int*)(ws + 2097152);              // 16 KB
    int*            starts = (int*)(ws + 2113536);              // 16 KB
    int*            cursor = (int*)(ws + 2129920);              // 16 KB
    float4*         spts   = (float4*)(ws + 2146304);           // 256 KB
    unsigned short* WnF    = (unsigned short*)(ws +  2408448);  // 32 KB
    unsigned short* W1b    = (unsigned short*)(ws +  2441216);  // 128 KB
    unsigned short* W2b    = (unsigned short*)(ws +  2572288);  // 128 KB
    unsigned short* featsb = (unsigned short*)(ws +  2703360);  // 4 MB
    unsigned short* Tb     = (unsigned short*)(ws +  6897664);  // 4 MB
    unsigned short* xb     = (unsigned short*)(ws + 11091968);  // 4 MB
    unsigned short* hb     = (unsigned short*)(ws + 15286272);  // 16 MB
    float4*         wfold  = (float4*)(ws + 32063488);          // 2 KB (~32.1 MB total)

    const int M = BB * NN;  // 16384

    prep_kernel<<<2641, 256, 0, stream>>>(Wn, W1, W2, feats, gn, bn_, mn, vn,
                                          WnF, W1b, W2b, featsb, counts, wfold);
    count_kernel<<<64, 256, 0, stream>>>(xyz, counts);
    scan_kernel<<<1, 1024, 0, stream>>>(counts, starts, cursor);
    scatter_kernel<<<64, 256, 0, stream>>>(xyz, cursor, spts);
    ball_query_binned_kernel<<<M, 64, 0, stream>>>(xyz, starts, spts, idx);

    // T' = sc1 * (feats @ WnF^T)   (M x 128, K=128) -> bf16
    mfma_gemm_kernel<3><<<dim3(M / 64, 1), 256, 0, stream>>>(
        featsb, WnF, gn, nullptr, nullptr, vn, nullptr, Tb, M, CC, CC);

    // x = relu(max_s (T'_gather + w'·g) + sh) -> bf16
    group_max_kernel<<<M / 8, 256, 0, stream>>>(xyz, Tb, wfold, idx, xb);

    // h = relu(bn(x @ W1^T))   (M x 512, K=128) -> bf16
    mfma_gemm_kernel<1><<<dim3(M / 64, HH / 128), 256, 0, stream>>>(
        xb, W1b, g1, b1, m1, v1, nullptr, hb, M, HH, CC);

    // out = relu(bn(h @ W2^T) + feats)   (M x 128, K=512) -> f32
    mfma_gemm_kernel<2><<<dim3(M / 64, 1), 256, 0, stream>>>(
        hb, W2b, g2, b2, m2, v2, feats, out, M, CC, HH);
}

// Round 9
// 155.927 us; speedup vs baseline: 1.7644x; 1.0203x over previous
//
#include <hip/hip_runtime.h>
#include <hip/hip_bf16.h>
#include <math.h>

// Problem dims (fixed by setup_inputs): B=4, N=4096, C=128, H=512, S=32
static constexpr int BB = 4;
static constexpr int NN = 4096;
static constexpr int CC = 128;
static constexpr int HH = 512;
static constexpr int SS = 32;
static constexpr float EPSF = 1e-5f;
static constexpr int NCELL = 1000;            // 10x10x10 per batch

typedef __bf16 bf16_t;
typedef bf16_t bf16x8 __attribute__((ext_vector_type(8)));
typedef float f32x4 __attribute__((ext_vector_type(4)));
typedef float f32x2 __attribute__((ext_vector_type(2)));

__device__ inline unsigned short f2bf(float f) {
    unsigned int u = __builtin_bit_cast(unsigned int, f);
    u += 0x7FFFu + ((u >> 16) & 1u);          // RNE
    return (unsigned short)(u >> 16);
}
__device__ inline float u2f(unsigned int u) {
    return __builtin_bit_cast(float, u);
}
__device__ inline int cell_of(float v) {
    int c = (int)(v * 10.0f);
    return c > 9 ? 9 : (c < 0 ? 0 : c);
}
// packed fp32 fma with scalar broadcast: D = a * {g,g} + c  (contracts to v_pk_fma_f32)
__device__ inline f32x2 pk_fma_b(f32x2 a, float g, f32x2 c) {
    const f32x2 gg = {g, g};
    return a * gg + c;
}

__device__ inline void gload_lds16(const void* g, void* l) {
    __builtin_amdgcn_global_load_lds(
        (const __attribute__((address_space(1))) unsigned int*)g,
        (__attribute__((address_space(3))) unsigned int*)l, 16, 0, 0);
}

// ---------------------------------------------------------------------------
// Prep: pack weights to bf16 + wfold.  577 blocks.
// ---------------------------------------------------------------------------
__global__ __launch_bounds__(256)
void prep_kernel(const float* __restrict__ Wn, const float* __restrict__ W1,
                 const float* __restrict__ W2,
                 const float* __restrict__ gn, const float* __restrict__ bnv,
                 const float* __restrict__ mn, const float* __restrict__ vn,
                 unsigned short* __restrict__ WnF, unsigned short* __restrict__ W1b,
                 unsigned short* __restrict__ W2b, float4* __restrict__ wfold)
{
    const int blk = blockIdx.x;
    const int t   = threadIdx.x;
    if (blk < 576) {
        const int i = blk * 256 + t;
        if (i < 16384) {
            const int o = i >> 7, c = i & 127;
            WnF[i] = f2bf(Wn[o * 131 + 3 + c]);
        } else if (i < 16384 + 65536) {
            const int k = i - 16384;
            W1b[k] = f2bf(W1[k]);
        } else if (i < 16384 + 131072) {
            const int k = i - 16384 - 65536;
            W2b[k] = f2bf(W2[k]);
        }
    } else {
        // wfold[o] = {sc*w0, sc*w1, sc*w2, sh};  sc = gn/sqrt(vn+eps), sh = bnv - mn*sc
        if (t < CC) {
            const float sc = gn[t] / sqrtf(vn[t] + EPSF);
            wfold[t] = make_float4(sc * Wn[t * 131 + 0], sc * Wn[t * 131 + 1],
                                   sc * Wn[t * 131 + 2], bnv[t] - mn[t] * sc);
        }
    }
}

// ---------------------------------------------------------------------------
// Binning (fused count+scan+scatter): one block per batch, 1024 threads.
// LDS histogram -> LDS scan -> starts to global -> LDS-cursor scatter.
// ---------------------------------------------------------------------------
__global__ __launch_bounds__(1024)
void bin_kernel(const float* __restrict__ xyz, int* __restrict__ starts,
                float4* __restrict__ spts)
{
    const int b = blockIdx.x;                  // 0..3
    const int t = threadIdx.x;                 // 0..1023

    __shared__ int cur[1024];
    __shared__ int ls[1024];

    cur[t] = 0;
    __syncthreads();

    int    cid[4];
    float4 pt[4];
    #pragma unroll
    for (int k = 0; k < 4; ++k) {
        const int n = k * 1024 + t;            // coalesced
        const float x = xyz[((size_t)b * NN + n) * 3 + 0];
        const float y = xyz[((size_t)b * NN + n) * 3 + 1];
        const float z = xyz[((size_t)b * NN + n) * 3 + 2];
        cid[k] = cell_of(z) * 100 + cell_of(y) * 10 + cell_of(x);
        pt[k]  = make_float4(x, y, z, __int_as_float(n));
        atomicAdd(&cur[cid[k]], 1);
    }
    __syncthreads();

    const int v = cur[t];
    ls[t] = v;
    __syncthreads();
    #pragma unroll
    for (int off = 1; off < 1024; off <<= 1) {
        const int add = (t >= off) ? ls[t - off] : 0;
        __syncthreads();
        ls[t] += add;
        __syncthreads();
    }
    const int ex = ls[t] - v;                  // exclusive prefix (cell t)
    if (t < NCELL) starts[b * NCELL + t] = b * NN + ex;
    if (b == 0 && t == 0) starts[BB * NCELL] = BB * NN;
    __syncthreads();
    cur[t] = ex;                               // per-cell cursor (local)
    __syncthreads();

    #pragma unroll
    for (int k = 0; k < 4; ++k) {
        const int pos = atomicAdd(&cur[cid[k]], 1);
        spts[(size_t)b * NN + pos] = pt[k];
    }
}

// ---------------------------------------------------------------------------
// Binned ball query: one wave per query; 9 contiguous candidate ranges;
// ballot-compact in-radius; rank-select the 32 smallest indices.
// ---------------------------------------------------------------------------
__global__ __launch_bounds__(64)
void ball_query_binned_kernel(const float* __restrict__ xyz,
                              const int* __restrict__ starts,
                              const float4* __restrict__ spts,
                              int* __restrict__ idx)
{
    const int p    = blockIdx.x;
    const int b    = p >> 12;
    const int lane = threadIdx.x;

    const float qx = xyz[p * 3 + 0];
    const float qy = xyz[p * 3 + 1];
    const float qz = xyz[p * 3 + 2];
    const int cx = cell_of(qx), cy = cell_of(qy), cz = cell_of(qz);
    const int xlo = cx > 0 ? cx - 1 : 0;
    const int xhi = cx < 9 ? cx + 1 : 9;

    __shared__ int list[128];
    __shared__ int res[SS];
    int cnt = 0;

    for (int dz = -1; dz <= 1; ++dz) {
        const int z2 = cz + dz;
        if (z2 < 0 || z2 > 9) continue;
        for (int dy = -1; dy <= 1; ++dy) {
            const int y2 = cy + dy;
            if (y2 < 0 || y2 > 9) continue;
            const int base = b * NCELL + z2 * 100 + y2 * 10;
            const int lo = starts[base + xlo];
            const int hi = starts[base + xhi + 1];
            for (int j0 = lo; j0 < hi; j0 += 64) {
                const int j = j0 + lane;
                bool in = false;
                int pi = 0;
                if (j < hi) {
                    const float4 s = spts[j];
                    float sq;
                    {
                        #pragma clang fp contract(off)   // match numpy at boundary
                        const float dx  = qx - s.x;
                        const float dyv = qy - s.y;
                        const float dzv = qz - s.z;
                        sq = dx * dx + dyv * dyv + dzv * dzv;
                    }
                    in = (sq <= 0.01f);
                    pi = __float_as_int(s.w);
                }
                const unsigned long long mask = __ballot(in);
                if (in) {
                    const int pos = cnt + __popcll(mask & ((1ull << lane) - 1ull));
                    if (pos < 128) list[pos] = pi;
                }
                cnt += (int)__popcll(mask);
            }
        }
    }
    __syncthreads();

    const int c = cnt < 128 ? cnt : 128;      // c >= 1 (self always in-radius)
    #pragma unroll
    for (int l0 = 0; l0 < 2; ++l0) {
        const int l = lane + l0 * 64;
        if (l < c) {
            const int v = list[l];
            int r = 0;
            for (int k = 0; k < c; ++k) r += (list[k] < v);
            if (r < SS) res[r] = v;
        }
    }
    __syncthreads();

    if (lane < SS) {
        const int m = c < SS ? c : SS;
        idx[(size_t)p * SS + lane] = (lane < m) ? res[lane] : res[0];
    }
}

// ---------------------------------------------------------------------------
// Stage 1 fused: x[p,o] = relu( max_s ( T'[j_s,o] + w'[o]·gxyz_s ) + sh[o] )
// T' = sc*T (scaled in GEMM epilogue), w' = sc*w, sh folded post-max.
// Block 256 thr = 8 points; 32 lanes/point, 4 channels/thread, packed fp32 fma.
// ---------------------------------------------------------------------------
__global__ __launch_bounds__(256)
void group_max_kernel(const float* __restrict__ xyz,
                      const unsigned short* __restrict__ T,   // pre-scaled bf16
                      const float4* __restrict__ wfold,
                      const int* __restrict__ idx, unsigned short* __restrict__ xout)
{
    const int t   = threadIdx.x;
    const int ptl = t >> 5;                    // 0..7 local point
    const int l   = t & 31;                    // lane within point
    const int p   = blockIdx.x * 8 + ptl;
    const int b   = p >> 12;

    __shared__ float4 sg[8][32];               // {gx, gy, gz, bitcast(j)}

    {
        const int j = idx[(size_t)p * SS + l];
        const float* q  = xyz + (size_t)p * 3;
        const float* pj = xyz + ((size_t)b * NN + j) * 3;
        sg[ptl][l] = make_float4((pj[0] - q[0]) / 0.1f,
                                 (pj[1] - q[1]) / 0.1f,
                                 (pj[2] - q[2]) / 0.1f, __int_as_float(j));
    }
    __syncthreads();

    const int c0 = l * 4;                      // this thread's 4 channels
    const float4 wa = wfold[c0 + 0], wb = wfold[c0 + 1];
    const float4 wc = wfold[c0 + 2], wd = wfold[c0 + 3];
    const f32x2 w0p0 = {wa.x, wb.x}, w1p0 = {wa.y, wb.y}, w2p0 = {wa.z, wb.z};
    const f32x2 w0p1 = {wc.x, wd.x}, w1p1 = {wc.y, wd.y}, w2p1 = {wc.z, wd.z};

    const unsigned short* Tb = T + (size_t)b * NN * CC;
    f32x2 mx0 = {-1e30f, -1e30f}, mx1 = {-1e30f, -1e30f};

    #pragma unroll 8
    for (int s = 0; s < SS; ++s) {
        const float4 g = sg[ptl][s];
        const int j = __float_as_int(g.w);
        const uint2 tv = *(const uint2*)(Tb + (size_t)j * CC + c0);
        f32x2 v0, v1;
        v0.x = u2f(tv.x << 16); v0.y = u2f(tv.x & 0xFFFF0000u);
        v1.x = u2f(tv.y << 16); v1.y = u2f(tv.y & 0xFFFF0000u);
        v0 = pk_fma_b(w0p0, g.x, v0); v0 = pk_fma_b(w1p0, g.y, v0); v0 = pk_fma_b(w2p0, g.z, v0);
        v1 = pk_fma_b(w0p1, g.x, v1); v1 = pk_fma_b(w1p1, g.y, v1); v1 = pk_fma_b(w2p1, g.z, v1);
        mx0.x = fmaxf(mx0.x, v0.x); mx0.y = fmaxf(mx0.y, v0.y);
        mx1.x = fmaxf(mx1.x, v1.x); mx1.y = fmaxf(mx1.y, v1.y);
    }

    const float r0 = fmaxf(mx0.x + wa.w, 0.f);
    const float r1 = fmaxf(mx0.y + wb.w, 0.f);
    const float r2 = fmaxf(mx1.x + wc.w, 0.f);
    const float r3 = fmaxf(mx1.y + wd.w, 0.f);
    uint2 o;
    o.x = (unsigned)f2bf(r0) | ((unsigned)f2bf(r1) << 16);
    o.y = (unsigned)f2bf(r2) | ((unsigned)f2bf(r3) << 16);
    *(uint2*)(xout + (size_t)p * CC + c0) = o;
}

// ---------------------------------------------------------------------------
// bf16 MFMA GEMM (B^T): BM=64, BNt in {64,128}, BK=64; 4 waves (2 x 2).
// Wave tile: 32 x BNt/2.  NF = BNt/32 n-frags per wave.
// MODE 1: bf16 relu(bn); MODE 2: f32 relu(bn + res); MODE 3: bf16 sc*z with
//   fp32 A input converted to bf16 during reg-staging (A ptr is fp32).
// ---------------------------------------------------------------------------
template<int MODE, int BNt>
__global__ __launch_bounds__(256, 2)
void mfma_gemm_kernel(const unsigned short* __restrict__ A, const unsigned short* __restrict__ W,
                      const float* __restrict__ g, const float* __restrict__ bb,
                      const float* __restrict__ mu, const float* __restrict__ var,
                      const float* __restrict__ res, void* __restrict__ outv,
                      int M, int Nout, int K)
{
    constexpr int BM = 64, BK = 64;
    constexpr int NF = BNt / 32;               // n-frags per wave
    __shared__ char smem[(BM + BNt) * BK * 2];
    char* sA = smem;
    char* sB = smem + BM * BK * 2;

    const int t    = threadIdx.x;
    const int lane = t & 63;
    const int w    = t >> 6;
    const int wm   = w >> 1;
    const int wn   = w & 1;
    const int m0   = blockIdx.x * BM;
    const int o0   = blockIdx.y * BNt;
    const int Kb   = K * 2;

    f32x4 acc[2][NF];
    #pragma unroll
    for (int i = 0; i < 2; ++i)
        #pragma unroll
        for (int j = 0; j < NF; ++j) acc[i][j] = f32x4{0.f, 0.f, 0.f, 0.f};

    const char* Ab = (const char*)A;
    const float* Af = (const float*)A;         // MODE 3: A is fp32
    const char* Wb = (const char*)W;

    for (int kc = 0; kc < K; kc += BK) {
        const int kcb = kc * 2;
        // ---- A tile: 64 rows x 128 B (8 chunks of 1 KB, 2 per wave)
        #pragma unroll
        for (int l = 0; l < 2; ++l) {
            const int q     = w * 2 + l;
            const int Lb    = q * 1024 + lane * 16;
            const int row   = Lb >> 7;
            const int inrow = Lb & 127;
            const int sw    = inrow ^ ((row & 7) << 4);
            if constexpr (MODE == 3) {
                // reg-stage fp32 -> bf16 into linear LDS (same swizzled layout)
                const float* src = Af + (size_t)(m0 + row) * K + kc + (sw >> 1);
                const float4 a0 = *(const float4*)(src);
                const float4 a1 = *(const float4*)(src + 4);
                uint4 pk;
                pk.x = (unsigned)f2bf(a0.x) | ((unsigned)f2bf(a0.y) << 16);
                pk.y = (unsigned)f2bf(a0.z) | ((unsigned)f2bf(a0.w) << 16);
                pk.z = (unsigned)f2bf(a1.x) | ((unsigned)f2bf(a1.y) << 16);
                pk.w = (unsigned)f2bf(a1.z) | ((unsigned)f2bf(a1.w) << 16);
                *(uint4*)(sA + Lb) = pk;
            } else {
                const char* src = Ab + (size_t)(m0 + row) * Kb + kcb + sw;
                gload_lds16(src, sA + q * 1024);
            }
        }
        // ---- B tile: BNt rows x 128 B (BNt/8 chunks, NF per wave)
        #pragma unroll
        for (int l = 0; l < NF; ++l) {
            const int q     = w * NF + l;
            const int Lb    = q * 1024 + lane * 16;
            const int row   = Lb >> 7;
            const int inrow = Lb & 127;
            const char* src = Wb + (size_t)(o0 + row) * Kb + kcb + (inrow ^ ((row & 7) << 4));
            gload_lds16(src, sB + q * 1024);
        }
        __syncthreads();

        #pragma unroll
        for (int ks = 0; ks < 2; ++ks) {
            const int kbyte = ks * 64 + (lane >> 4) * 16;
            bf16x8 af[2], bf[NF];
            #pragma unroll
            for (int i = 0; i < 2; ++i) {
                const int r = wm * 32 + i * 16 + (lane & 15);
                af[i] = *(const bf16x8*)(sA + r * 128 + (kbyte ^ ((r & 7) << 4)));
            }
            #pragma unroll
            for (int j = 0; j < NF; ++j) {
                const int r = wn * (BNt / 2) + j * 16 + (lane & 15);
                bf[j] = *(const bf16x8*)(sB + r * 128 + (kbyte ^ ((r & 7) << 4)));
            }
            #pragma unroll
            for (int i = 0; i < 2; ++i)
                #pragma unroll
                for (int j = 0; j < NF; ++j)
                    acc[i][j] = __builtin_amdgcn_mfma_f32_16x16x32_bf16(af[i], bf[j], acc[i][j], 0, 0, 0);
        }
        __syncthreads();
    }

    #pragma unroll
    for (int j = 0; j < NF; ++j) {
        const int col = o0 + wn * (BNt / 2) + j * 16 + (lane & 15);
        float scg = 1.f, sh = 0.f, mm = 0.f;
        if constexpr (MODE == 1 || MODE == 2) {
            scg = g[col] / sqrtf(var[col] + EPSF);
            mm  = mu[col];
            sh  = bb[col];
        }
        if constexpr (MODE == 3) {
            scg = g[col] / sqrtf(var[col] + EPSF);
        }
        #pragma unroll
        for (int i = 0; i < 2; ++i) {
            const int rowb = m0 + wm * 32 + i * 16 + (lane >> 4) * 4;
            #pragma unroll
            for (int r = 0; r < 4; ++r) {
                float z = acc[i][j][r];
                if constexpr (MODE == 1 || MODE == 2) z = (z - mm) * scg + sh;
                if constexpr (MODE == 3) z = z * scg;
                if constexpr (MODE == 2) z += res[(size_t)(rowb + r) * Nout + col];
                if constexpr (MODE == 1 || MODE == 2) z = fmaxf(z, 0.f);
                if constexpr (MODE == 2)
                    ((float*)outv)[(size_t)(rowb + r) * Nout + col] = z;
                else
                    ((unsigned short*)outv)[(size_t)(rowb + r) * Nout + col] = f2bf(z);
            }
        }
    }
}

// ---------------------------------------------------------------------------
extern "C" void kernel_launch(void* const* d_in, const int* in_sizes, int n_in,
                              void* d_out, int out_size, void* d_ws, size_t ws_size,
                              hipStream_t stream)
{
    const float* xyz   = (const float*)d_in[0];
    const float* feats = (const float*)d_in[1];
    const float* Wn    = (const float*)d_in[2];
    const float* gn    = (const float*)d_in[3];
    const float* bn_   = (const float*)d_in[4];
    const float* mn    = (const float*)d_in[5];
    const float* vn    = (const float*)d_in[6];
    const float* W1    = (const float*)d_in[7];
    const float* g1    = (const float*)d_in[8];
    const float* b1    = (const float*)d_in[9];
    const float* m1    = (const float*)d_in[10];
    const float* v1    = (const float*)d_in[11];
    const float* W2    = (const float*)d_in[12];
    const float* g2    = (const float*)d_in[13];
    const float* b2    = (const float*)d_in[14];
    const float* m2    = (const float*)d_in[15];
    const float* v2    = (const float*)d_in[16];
    float* out = (float*)d_out;

    // workspace layout (bytes, 256-aligned)
    char* ws = (char*)d_ws;
    int*            idx    = (int*)(ws);                        // 2 MB
    int*            starts = (int*)(ws + 2097152);              // 16 KB (4001 ints)
    float4*         spts   = (float4*)(ws + 2113536);           // 256 KB
    unsigned short* WnF    = (unsigned short*)(ws + 2375680);   // 32 KB
    unsigned short* W1b    = (unsigned short*)(ws + 2408448);   // 128 KB
    unsigned short* W2b    = (unsigned short*)(ws + 2539520);   // 128 KB
    unsigned short* Tb     = (unsigned short*)(ws + 2670592);   // 4 MB
    unsigned short* xb     = (unsigned short*)(ws + 6864896);   // 4 MB
    unsigned short* hb     = (unsigned short*)(ws + 11059200);  // 16 MB
    float4*         wfold  = (float4*)(ws + 27836416);          // 2 KB (~27.8 MB total)

    const int M = BB * NN;  // 16384

    prep_kernel<<<577, 256, 0, stream>>>(Wn, W1, W2, gn, bn_, mn, vn,
                                         WnF, W1b, W2b, wfold);
    bin_kernel<<<BB, 1024, 0, stream>>>(xyz, starts, spts);
    ball_query_binned_kernel<<<M, 64, 0, stream>>>(xyz, starts, spts, idx);

    // T' = sc1 * (feats @ WnF^T)   (M x 128, K=128) -> bf16; A fp32, converted in-staging
    mfma_gemm_kernel<3, 128><<<dim3(M / 64, 1), 256, 0, stream>>>(
        (const unsigned short*)feats, WnF, gn, nullptr, nullptr, vn, nullptr, Tb, M, CC, CC);

    // x = relu(max_s (T'_gather + w'·g) + sh) -> bf16
    group_max_kernel<<<M / 8, 256, 0, stream>>>(xyz, Tb, wfold, idx, xb);

    // h = relu(bn(x @ W1^T))   (M x 512, K=128) -> bf16
    mfma_gemm_kernel<1, 128><<<dim3(M / 64, HH / 128), 256, 0, stream>>>(
        xb, W1b, g1, b1, m1, v1, nullptr, hb, M, HH, CC);

    // out = relu(bn(h @ W2^T) + feats)   (M x 128, K=512) -> f32; BN=64 for occupancy
    mfma_gemm_kernel<2, 64><<<dim3(M / 64, CC / 64), 256, 0, stream>>>(
        hb, W2b, g2, b2, m2, v2, feats, out, M, CC, HH);
}

// Round 14
// 151.005 us; speedup vs baseline: 1.8219x; 1.0326x over previous
//
#include <hip/hip_runtime.h>
#include <hip/hip_bf16.h>
#include <math.h>

// Problem dims (fixed by setup_inputs): B=4, N=4096, C=128, H=512, S=32
static constexpr int BB = 4;
static constexpr int NN = 4096;
static constexpr int CC = 128;
static constexpr int HH = 512;
static constexpr int SS = 32;
static constexpr float EPSF = 1e-5f;
static constexpr int NCELL = 1000;            // 10x10x10 per batch

typedef __bf16 bf16_t;
typedef bf16_t bf16x8 __attribute__((ext_vector_type(8)));
typedef float f32x4 __attribute__((ext_vector_type(4)));
typedef float f32x2 __attribute__((ext_vector_type(2)));

__device__ inline unsigned short f2bf(float f) {
    unsigned int u = __builtin_bit_cast(unsigned int, f);
    u += 0x7FFFu + ((u >> 16) & 1u);          // RNE
    return (unsigned short)(u >> 16);
}
__device__ inline float u2f(unsigned int u) {
    return __builtin_bit_cast(float, u);
}
__device__ inline int cell_of(float v) {
    int c = (int)(v * 10.0f);
    return c > 9 ? 9 : (c < 0 ? 0 : c);
}
// packed fp32 fma with scalar broadcast: D = a * {g,g} + c  (contracts to v_pk_fma_f32)
__device__ inline f32x2 pk_fma_b(f32x2 a, float g, f32x2 c) {
    const f32x2 gg = {g, g};
    return a * gg + c;
}

__device__ inline void gload_lds16(const void* g, void* l) {
    __builtin_amdgcn_global_load_lds(
        (const __attribute__((address_space(1))) unsigned int*)g,
        (__attribute__((address_space(3))) unsigned int*)l, 16, 0, 0);
}

// ---------------------------------------------------------------------------
// Fused prep + binning.  1024 threads, 149 blocks:
//   [0,144)  : weight pack to bf16 (147456 elems)
//   144      : wfold
//   [145,149): per-batch fused count+scan+scatter (b = blk-145)
// Weight blocks execute on other CUs while the 4 bin blocks run their scan.
// ---------------------------------------------------------------------------
__global__ __launch_bounds__(1024)
void prep_bin_kernel(const float* __restrict__ Wn, const float* __restrict__ W1,
                     const float* __restrict__ W2,
                     const float* __restrict__ gn, const float* __restrict__ bnv,
                     const float* __restrict__ mn, const float* __restrict__ vn,
                     const float* __restrict__ xyz,
                     unsigned short* __restrict__ WnF, unsigned short* __restrict__ W1b,
                     unsigned short* __restrict__ W2b, float4* __restrict__ wfold,
                     int* __restrict__ starts, float4* __restrict__ spts)
{
    const int blk = blockIdx.x;
    const int t   = threadIdx.x;

    __shared__ int cur[1024];
    __shared__ int ls[1024];

    if (blk < 144) {
        const int i = blk * 1024 + t;             // < 147456 exactly
        if (i < 16384) {
            const int o = i >> 7, c = i & 127;
            WnF[i] = f2bf(Wn[o * 131 + 3 + c]);
        } else if (i < 81920) {
            W1b[i - 16384] = f2bf(W1[i - 16384]);
        } else {
            W2b[i - 81920] = f2bf(W2[i - 81920]);
        }
        return;
    }
    if (blk == 144) {
        // wfold[o] = {sc*w0, sc*w1, sc*w2, sh}
        if (t < CC) {
            const float sc = gn[t] / sqrtf(vn[t] + EPSF);
            wfold[t] = make_float4(sc * Wn[t * 131 + 0], sc * Wn[t * 131 + 1],
                                   sc * Wn[t * 131 + 2], bnv[t] - mn[t] * sc);
        }
        return;
    }

    // ---- binning for batch b
    const int b = blk - 145;
    cur[t] = 0;
    __syncthreads();

    int    cid[4];
    float4 pt[4];
    #pragma unroll
    for (int k = 0; k < 4; ++k) {
        const int n = k * 1024 + t;               // coalesced
        const float x = xyz[((size_t)b * NN + n) * 3 + 0];
        const float y = xyz[((size_t)b * NN + n) * 3 + 1];
        const float z = xyz[((size_t)b * NN + n) * 3 + 2];
        cid[k] = cell_of(z) * 100 + cell_of(y) * 10 + cell_of(x);
        pt[k]  = make_float4(x, y, z, __int_as_float(n));
        atomicAdd(&cur[cid[k]], 1);
    }
    __syncthreads();

    const int v = cur[t];
    ls[t] = v;
    __syncthreads();
    #pragma unroll
    for (int off = 1; off < 1024; off <<= 1) {
        const int add = (t >= off) ? ls[t - off] : 0;
        __syncthreads();
        ls[t] += add;
        __syncthreads();
    }
    const int ex = ls[t] - v;                     // exclusive prefix (cell t)
    if (t < NCELL) starts[b * NCELL + t] = b * NN + ex;
    if (b == 0 && t == 0) starts[BB * NCELL] = BB * NN;
    __syncthreads();
    cur[t] = ex;
    __syncthreads();

    #pragma unroll
    for (int k = 0; k < 4; ++k) {
        const int pos = atomicAdd(&cur[cid[k]], 1);
        spts[(size_t)b * NN + pos] = pt[k];
    }
}

// ---------------------------------------------------------------------------
// Fused T-GEMM + ball query.  256 threads.
//   blocks [0,256)    : T' = sc1*(feats @ WnF^T) tile (BM=64, BN=128, K=128),
//                       fp32 A converted to bf16 during reg-staging.
//   blocks [256,4352) : binned ball query, 4 queries/block (1 wave each).
// bq waves fill CU slots left idle by the MFMA-bound GEMM blocks.
// ---------------------------------------------------------------------------
__global__ __launch_bounds__(256, 2)
void tgemm_bq_kernel(const float* __restrict__ feats, const unsigned short* __restrict__ WnF,
                     const float* __restrict__ gn, const float* __restrict__ vn,
                     unsigned short* __restrict__ Tb,
                     const float* __restrict__ xyz, const int* __restrict__ starts,
                     const float4* __restrict__ spts, int* __restrict__ idx)
{
    __shared__ char smem[(64 + 128) * 128];       // 24576 B

    if (blockIdx.x < 256) {
        // ================= T-GEMM tile =================
        char* sA = smem;
        char* sB = smem + 64 * 128;
        const int t    = threadIdx.x;
        const int lane = t & 63;
        const int w    = t >> 6;
        const int wm   = w >> 1;
        const int wn   = w & 1;
        const int m0   = blockIdx.x * 64;

        f32x4 acc[2][4];
        #pragma unroll
        for (int i = 0; i < 2; ++i)
            #pragma unroll
            for (int j = 0; j < 4; ++j) acc[i][j] = f32x4{0.f, 0.f, 0.f, 0.f};

        const char* Wb = (const char*)WnF;

        for (int kc = 0; kc < CC; kc += 64) {
            #pragma unroll
            for (int l = 0; l < 2; ++l) {
                const int q     = w * 2 + l;
                const int Lb    = q * 1024 + lane * 16;
                const int row   = Lb >> 7;
                const int inrow = Lb & 127;
                const int sw    = inrow ^ ((row & 7) << 4);
                const float* src = feats + (size_t)(m0 + row) * CC + kc + (sw >> 1);
                const float4 a0 = *(const float4*)(src);
                const float4 a1 = *(const float4*)(src + 4);
                uint4 pk;
                pk.x = (unsigned)f2bf(a0.x) | ((unsigned)f2bf(a0.y) << 16);
                pk.y = (unsigned)f2bf(a0.z) | ((unsigned)f2bf(a0.w) << 16);
                pk.z = (unsigned)f2bf(a1.x) | ((unsigned)f2bf(a1.y) << 16);
                pk.w = (unsigned)f2bf(a1.z) | ((unsigned)f2bf(a1.w) << 16);
                *(uint4*)(sA + Lb) = pk;
            }
            #pragma unroll
            for (int l = 0; l < 4; ++l) {
                const int q     = w * 4 + l;
                const int Lb    = q * 1024 + lane * 16;
                const int row   = Lb >> 7;
                const int inrow = Lb & 127;
                const char* src = Wb + (size_t)row * 256 + kc * 2 + (inrow ^ ((row & 7) << 4));
                gload_lds16(src, sB + q * 1024);
            }
            __syncthreads();

            #pragma unroll
            for (int ks = 0; ks < 2; ++ks) {
                const int kbyte = ks * 64 + (lane >> 4) * 16;
                bf16x8 af[2], bf[4];
                #pragma unroll
                for (int i = 0; i < 2; ++i) {
                    const int r = wm * 32 + i * 16 + (lane & 15);
                    af[i] = *(const bf16x8*)(sA + r * 128 + (kbyte ^ ((r & 7) << 4)));
                }
                #pragma unroll
                for (int j = 0; j < 4; ++j) {
                    const int r = wn * 64 + j * 16 + (lane & 15);
                    bf[j] = *(const bf16x8*)(sB + r * 128 + (kbyte ^ ((r & 7) << 4)));
                }
                #pragma unroll
                for (int i = 0; i < 2; ++i)
                    #pragma unroll
                    for (int j = 0; j < 4; ++j)
                        acc[i][j] = __builtin_amdgcn_mfma_f32_16x16x32_bf16(af[i], bf[j], acc[i][j], 0, 0, 0);
            }
            __syncthreads();
        }

        #pragma unroll
        for (int j = 0; j < 4; ++j) {
            const int col = wn * 64 + j * 16 + (lane & 15);
            const float scg = gn[col] / sqrtf(vn[col] + EPSF);
            #pragma unroll
            for (int i = 0; i < 2; ++i) {
                const int rowb = m0 + wm * 32 + i * 16 + (lane >> 4) * 4;
                #pragma unroll
                for (int r = 0; r < 4; ++r)
                    Tb[(size_t)(rowb + r) * CC + col] = f2bf(acc[i][j][r] * scg);
            }
        }
    } else {
        // ================= ball query (4 queries, 1 wave each) =================
        const int t    = threadIdx.x;
        const int wv   = t >> 6;
        const int lane = t & 63;
        const int p    = (blockIdx.x - 256) * 4 + wv;
        const int b    = p >> 12;

        int* lbase = (int*)smem + wv * 160;       // per-wave: list[128] + res[32]
        int* list  = lbase;
        int* res   = lbase + 128;

        const float qx = xyz[p * 3 + 0];
        const float qy = xyz[p * 3 + 1];
        const float qz = xyz[p * 3 + 2];
        const int cx = cell_of(qx), cy = cell_of(qy), cz = cell_of(qz);
        const int xlo = cx > 0 ? cx - 1 : 0;
        const int xhi = cx < 9 ? cx + 1 : 9;

        int cnt = 0;
        for (int dz = -1; dz <= 1; ++dz) {
            const int z2 = cz + dz;
            if (z2 < 0 || z2 > 9) continue;
            for (int dy = -1; dy <= 1; ++dy) {
                const int y2 = cy + dy;
                if (y2 < 0 || y2 > 9) continue;
                const int base = b * NCELL + z2 * 100 + y2 * 10;
                const int lo = starts[base + xlo];
                const int hi = starts[base + xhi + 1];
                for (int j0 = lo; j0 < hi; j0 += 64) {
                    const int j = j0 + lane;
                    bool in = false;
                    int pi = 0;
                    if (j < hi) {
                        const float4 s = spts[j];
                        float sq;
                        {
                            #pragma clang fp contract(off)   // match numpy at boundary
                            const float dx  = qx - s.x;
                            const float dyv = qy - s.y;
                            const float dzv = qz - s.z;
                            sq = dx * dx + dyv * dyv + dzv * dzv;
                        }
                        in = (sq <= 0.01f);
                        pi = __float_as_int(s.w);
                    }
                    const unsigned long long mask = __ballot(in);
                    if (in) {
                        const int pos = cnt + __popcll(mask & ((1ull << lane) - 1ull));
                        if (pos < 128) list[pos] = pi;
                    }
                    cnt += (int)__popcll(mask);
                }
            }
        }
        __syncthreads();                          // uniform: all 4 waves reach

        const int c = cnt < 128 ? cnt : 128;      // c >= 1 (self always in-radius)
        #pragma unroll
        for (int l0 = 0; l0 < 2; ++l0) {
            const int l = lane + l0 * 64;
            if (l < c) {
                const int v = list[l];
                int r = 0;
                for (int k = 0; k < c; ++k) r += (list[k] < v);
                if (r < SS) res[r] = v;
            }
        }
        __syncthreads();

        if (lane < SS) {
            const int m = c < SS ? c : SS;
            idx[(size_t)p * SS + lane] = (lane < m) ? res[lane] : res[0];
        }
    }
}

// ---------------------------------------------------------------------------
// Stage 1 fused: x[p,o] = relu( max_s ( T'[j_s,o] + w'[o]·gxyz_s ) + sh[o] )
// Block 256 thr = 8 points; 32 lanes/point, 4 channels/thread, packed fp32 fma.
// ---------------------------------------------------------------------------
__global__ __launch_bounds__(256)
void group_max_kernel(const float* __restrict__ xyz,
                      const unsigned short* __restrict__ T,   // pre-scaled bf16
                      const float4* __restrict__ wfold,
                      const int* __restrict__ idx, unsigned short* __restrict__ xout)
{
    const int t   = threadIdx.x;
    const int ptl = t >> 5;                    // 0..7 local point
    const int l   = t & 31;                    // lane within point
    const int p   = blockIdx.x * 8 + ptl;
    const int b   = p >> 12;

    __shared__ float4 sg[8][32];               // {gx, gy, gz, bitcast(j)}

    {
        const int j = idx[(size_t)p * SS + l];
        const float* q  = xyz + (size_t)p * 3;
        const float* pj = xyz + ((size_t)b * NN + j) * 3;
        sg[ptl][l] = make_float4((pj[0] - q[0]) / 0.1f,
                                 (pj[1] - q[1]) / 0.1f,
                                 (pj[2] - q[2]) / 0.1f, __int_as_float(j));
    }
    __syncthreads();

    const int c0 = l * 4;                      // this thread's 4 channels
    const float4 wa = wfold[c0 + 0], wb = wfold[c0 + 1];
    const float4 wc = wfold[c0 + 2], wd = wfold[c0 + 3];
    const f32x2 w0p0 = {wa.x, wb.x}, w1p0 = {wa.y, wb.y}, w2p0 = {wa.z, wb.z};
    const f32x2 w0p1 = {wc.x, wd.x}, w1p1 = {wc.y, wd.y}, w2p1 = {wc.z, wd.z};

    const unsigned short* Tbp = T + (size_t)b * NN * CC;
    f32x2 mx0 = {-1e30f, -1e30f}, mx1 = {-1e30f, -1e30f};

    #pragma unroll 8
    for (int s = 0; s < SS; ++s) {
        const float4 g = sg[ptl][s];
        const int j = __float_as_int(g.w);
        const uint2 tv = *(const uint2*)(Tbp + (size_t)j * CC + c0);
        f32x2 v0, v1;
        v0.x = u2f(tv.x << 16); v0.y = u2f(tv.x & 0xFFFF0000u);
        v1.x = u2f(tv.y << 16); v1.y = u2f(tv.y & 0xFFFF0000u);
        v0 = pk_fma_b(w0p0, g.x, v0); v0 = pk_fma_b(w1p0, g.y, v0); v0 = pk_fma_b(w2p0, g.z, v0);
        v1 = pk_fma_b(w0p1, g.x, v1); v1 = pk_fma_b(w1p1, g.y, v1); v1 = pk_fma_b(w2p1, g.z, v1);
        mx0.x = fmaxf(mx0.x, v0.x); mx0.y = fmaxf(mx0.y, v0.y);
        mx1.x = fmaxf(mx1.x, v1.x); mx1.y = fmaxf(mx1.y, v1.y);
    }

    const float r0 = fmaxf(mx0.x + wa.w, 0.f);
    const float r1 = fmaxf(mx0.y + wb.w, 0.f);
    const float r2 = fmaxf(mx1.x + wc.w, 0.f);
    const float r3 = fmaxf(mx1.y + wd.w, 0.f);
    uint2 o;
    o.x = (unsigned)f2bf(r0) | ((unsigned)f2bf(r1) << 16);
    o.y = (unsigned)f2bf(r2) | ((unsigned)f2bf(r3) << 16);
    *(uint2*)(xout + (size_t)p * CC + c0) = o;
}

// ---------------------------------------------------------------------------
// bf16 MFMA GEMM (B^T): BM=64, BNt in {64,128}, BK=64; 4 waves (2 x 2).
// MODE 1: bf16 relu(bn); MODE 2: f32 relu(bn + res).
// ---------------------------------------------------------------------------
template<int MODE, int BNt>
__global__ __launch_bounds__(256, 2)
void mfma_gemm_kernel(const unsigned short* __restrict__ A, const unsigned short* __restrict__ W,
                      const float* __restrict__ g, const float* __restrict__ bb,
                      const float* __restrict__ mu, const float* __restrict__ var,
                      const float* __restrict__ res, void* __restrict__ outv,
                      int M, int Nout, int K)
{
    constexpr int BM = 64, BK = 64;
    constexpr int NF = BNt / 32;               // n-frags per wave
    __shared__ char smem[(BM + BNt) * BK * 2];
    char* sA = smem;
    char* sB = smem + BM * BK * 2;

    const int t    = threadIdx.x;
    const int lane = t & 63;
    const int w    = t >> 6;
    const int wm   = w >> 1;
    const int wn   = w & 1;
    const int m0   = blockIdx.x * BM;
    const int o0   = blockIdx.y * BNt;
    const int Kb   = K * 2;

    f32x4 acc[2][NF];
    #pragma unroll
    for (int i = 0; i < 2; ++i)
        #pragma unroll
        for (int j = 0; j < NF; ++j) acc[i][j] = f32x4{0.f, 0.f, 0.f, 0.f};

    const char* Ab = (const char*)A;
    const char* Wb = (const char*)W;

    for (int kc = 0; kc < K; kc += BK) {
        const int kcb = kc * 2;
        #pragma unroll
        for (int l = 0; l < 2; ++l) {
            const int q     = w * 2 + l;
            const int Lb    = q * 1024 + lane * 16;
            const int row   = Lb >> 7;
            const int inrow = Lb & 127;
            const char* src = Ab + (size_t)(m0 + row) * Kb + kcb + (inrow ^ ((row & 7) << 4));
            gload_lds16(src, sA + q * 1024);
        }
        #pragma unroll
        for (int l = 0; l < NF; ++l) {
            const int q     = w * NF + l;
            const int Lb    = q * 1024 + lane * 16;
            const int row   = Lb >> 7;
            const int inrow = Lb & 127;
            const char* src = Wb + (size_t)(o0 + row) * Kb + kcb + (inrow ^ ((row & 7) << 4));
            gload_lds16(src, sB + q * 1024);
        }
        __syncthreads();

        #pragma unroll
        for (int ks = 0; ks < 2; ++ks) {
            const int kbyte = ks * 64 + (lane >> 4) * 16;
            bf16x8 af[2], bf[NF];
            #pragma unroll
            for (int i = 0; i < 2; ++i) {
                const int r = wm * 32 + i * 16 + (lane & 15);
                af[i] = *(const bf16x8*)(sA + r * 128 + (kbyte ^ ((r & 7) << 4)));
            }
            #pragma unroll
            for (int j = 0; j < NF; ++j) {
                const int r = wn * (BNt / 2) + j * 16 + (lane & 15);
                bf[j] = *(const bf16x8*)(sB + r * 128 + (kbyte ^ ((r & 7) << 4)));
            }
            #pragma unroll
            for (int i = 0; i < 2; ++i)
                #pragma unroll
                for (int j = 0; j < NF; ++j)
                    acc[i][j] = __builtin_amdgcn_mfma_f32_16x16x32_bf16(af[i], bf[j], acc[i][j], 0, 0, 0);
        }
        __syncthreads();
    }

    #pragma unroll
    for (int j = 0; j < NF; ++j) {
        const int col = o0 + wn * (BNt / 2) + j * 16 + (lane & 15);
        const float scg = g[col] / sqrtf(var[col] + EPSF);
        const float mm  = mu[col];
        const float sh  = bb[col];
        #pragma unroll
        for (int i = 0; i < 2; ++i) {
            const int rowb = m0 + wm * 32 + i * 16 + (lane >> 4) * 4;
            #pragma unroll
            for (int r = 0; r < 4; ++r) {
                float z = acc[i][j][r];
                z = (z - mm) * scg + sh;
                if constexpr (MODE == 2) z += res[(size_t)(rowb + r) * Nout + col];
                z = fmaxf(z, 0.f);
                if constexpr (MODE == 2)
                    ((float*)outv)[(size_t)(rowb + r) * Nout + col] = z;
                else
                    ((unsigned short*)outv)[(size_t)(rowb + r) * Nout + col] = f2bf(z);
            }
        }
    }
}

// ---------------------------------------------------------------------------
extern "C" void kernel_launch(void* const* d_in, const int* in_sizes, int n_in,
                              void* d_out, int out_size, void* d_ws, size_t ws_size,
                              hipStream_t stream)
{
    const float* xyz   = (const float*)d_in[0];
    const float* feats = (const float*)d_in[1];
    const float* Wn    = (const float*)d_in[2];
    const float* gn    = (const float*)d_in[3];
    const float* bn_   = (const float*)d_in[4];
    const float* mn    = (const float*)d_in[5];
    const float* vn    = (const float*)d_in[6];
    const float* W1    = (const float*)d_in[7];
    const float* g1    = (const float*)d_in[8];
    const float* b1    = (const float*)d_in[9];
    const float* m1    = (const float*)d_in[10];
    const float* v1    = (const float*)d_in[11];
    const float* W2    = (const float*)d_in[12];
    const float* g2    = (const float*)d_in[13];
    const float* b2    = (const float*)d_in[14];
    const float* m2    = (const float*)d_in[15];
    const float* v2    = (const float*)d_in[16];
    float* out = (float*)d_out;

    // workspace layout (bytes, 256-aligned)
    char* ws = (char*)d_ws;
    int*            idx    = (int*)(ws);                        // 2 MB
    int*            starts = (int*)(ws + 2097152);              // 16 KB (4001 ints)
    float4*         spts   = (float4*)(ws + 2113536);           // 256 KB
    unsigned short* WnF    = (unsigned short*)(ws + 2375680);   // 32 KB
    unsigned short* W1b    = (unsigned short*)(ws + 2408448);   // 128 KB
    unsigned short* W2b    = (unsigned short*)(ws + 2539520);   // 128 KB
    unsigned short* Tb     = (unsigned short*)(ws + 2670592);   // 4 MB
    unsigned short* xb     = (unsigned short*)(ws + 6864896);   // 4 MB
    unsigned short* hb     = (unsigned short*)(ws + 11059200);  // 16 MB
    float4*         wfold  = (float4*)(ws + 27836416);          // 2 KB (~27.8 MB total)

    const int M = BB * NN;  // 16384

    // 1) weights pack + wfold + binning (fused)
    prep_bin_kernel<<<149, 1024, 0, stream>>>(Wn, W1, W2, gn, bn_, mn, vn, xyz,
                                              WnF, W1b, W2b, wfold, starts, spts);

    // 2) T' = sc1*(feats @ WnF^T) -> bf16   ∥   ball query (fused launch)
    tgemm_bq_kernel<<<256 + M / 4, 256, 0, stream>>>(feats, WnF, gn, vn, Tb,
                                                     xyz, starts, spts, idx);

    // 3) x = relu(max_s (T'_gather + w'·g) + sh) -> bf16
    group_max_kernel<<<M / 8, 256, 0, stream>>>(xyz, Tb, wfold, idx, xb);

    // 4) h = relu(bn(x @ W1^T))   (M x 512, K=128) -> bf16
    mfma_gemm_kernel<1, 128><<<dim3(M / 64, HH / 128), 256, 0, stream>>>(
        xb, W1b, g1, b1, m1, v1, nullptr, hb, M, HH, CC);

    // 5) out = relu(bn(h @ W2^T) + feats)   (M x 128, K=512) -> f32
    mfma_gemm_kernel<2, 64><<<dim3(M / 64, CC / 64), 256, 0, stream>>>(
        hb, W2b, g2, b2, m2, v2, feats, out, M, CC, HH);
}